// Round 3
// baseline (2695.115 us; speedup 1.0000x reference)
//
#include <hip/hip_runtime.h>

#define NUM_E   16384
#define DIM     256
#define NROWS   8192      // B*H*W
#define HW      1024      // H*W
#define NSPL    64        // k_score grid.x; each block covers 256 cols (2 strips)
#define BM      128
#define BN      128
#define NT      2
#define BK      32

// 16-B chunk swizzle: rows 0..127, chunks 0..3 (BK=32 shorts = 4 x 16B)
#define SWZ(r) ((((r) >> 1) ^ ((r) >> 3)) & 3)

typedef __bf16 bf16x8 __attribute__((ext_vector_type(8)));
typedef float  f32x4  __attribute__((ext_vector_type(4)));
typedef float  f32x16 __attribute__((ext_vector_type(16)));

__device__ __forceinline__ unsigned short f2bf(float x) {
    unsigned u = __float_as_uint(x);
    unsigned r = (u + 0x7fffu + ((u >> 16) & 1u)) >> 16;
    return (unsigned short)r;
}
__device__ __forceinline__ float bf2f(unsigned short h) {
    return __uint_as_float(((unsigned)h) << 16);
}
__device__ __forceinline__ void async_copy16(const void* g, void* l) {
    __builtin_amdgcn_global_load_lds(
        (const __attribute__((address_space(1))) unsigned int*)g,
        (__attribute__((address_space(3))) unsigned int*)l, 16, 0, 0);
}
__device__ __forceinline__ void top2_merge(float& V1, int& I1, float& V2, int& I2,
                                           float w, int j) {
    if (w > V1 || (w == V1 && j < I1)) { V2 = V1; I2 = I1; V1 = w; I1 = j; }
    else if (w > V2 || (w == V2 && j < I2)) { V2 = w; I2 = j; }
}

// ---------------- inverse norms ----------------
__global__ void k_inv_e(const float* __restrict__ emb, float* __restrict__ inv_e) {
    int w = threadIdx.x >> 6, lane = threadIdx.x & 63;
    int k = blockIdx.x * 4 + w;
    float4 v = *(const float4*)(emb + (size_t)k * DIM + lane * 4);
    float s = v.x*v.x + v.y*v.y + v.z*v.z + v.w*v.w;
    for (int off = 32; off > 0; off >>= 1) s += __shfl_down(s, off);
    if (lane == 0) inv_e[k] = 1.0f / fmaxf(sqrtf(s), 1e-12f);
}

__global__ void k_inv_z(const float* __restrict__ z, float* __restrict__ inv_z) {
    int n = blockIdx.x * 256 + threadIdx.x;
    int b = n >> 10, hw = n & 1023;
    const float* p = z + (size_t)b * DIM * HW + hw;
    float s = 0.f;
    #pragma unroll 8
    for (int c = 0; c < DIM; c++) { float v = p[c * HW]; s += v * v; }
    inv_z[n] = 1.0f / fmaxf(sqrtf(s), 1e-12f);
}

// ---------------- prep: normalized bf16 hi/lo splits ----------------
__global__ void k_prep_z(const float* __restrict__ z, const float* __restrict__ inv_z,
                         unsigned short* __restrict__ Zh, unsigned short* __restrict__ Zl) {
    __shared__ float T[64 * 68];
    int t = threadIdx.x;
    int n0 = blockIdx.x * 64, c0 = blockIdx.y * 64;
    int b = n0 >> 10, hw0 = n0 & 1023;
    #pragma unroll
    for (int i = 0; i < 4; i++) {
        int f = t + 256 * i;
        int cc = f >> 4, n4 = (f & 15) * 4;
        float4 v  = *(const float4*)(z + (size_t)(b * DIM + c0 + cc) * HW + hw0 + n4);
        float4 iv = *(const float4*)(inv_z + n0 + n4);
        v.x *= iv.x; v.y *= iv.y; v.z *= iv.z; v.w *= iv.w;
        *(float4*)&T[cc * 68 + n4] = v;
    }
    __syncthreads();
    #pragma unroll
    for (int i = 0; i < 4; i++) {
        int f = t + 256 * i;
        int nn = f >> 4, c4 = (f & 15) * 4;
        ushort4 h, lo;
        float x;
        x = T[(c4+0)*68 + nn]; h.x = f2bf(x); lo.x = f2bf(x - bf2f(h.x));
        x = T[(c4+1)*68 + nn]; h.y = f2bf(x); lo.y = f2bf(x - bf2f(h.y));
        x = T[(c4+2)*68 + nn]; h.z = f2bf(x); lo.z = f2bf(x - bf2f(h.z));
        x = T[(c4+3)*68 + nn]; h.w = f2bf(x); lo.w = f2bf(x - bf2f(h.w));
        size_t o = (size_t)(n0 + nn) * DIM + c0 + c4;
        *(ushort4*)(Zh + o) = h;
        *(ushort4*)(Zl + o) = lo;
    }
}

__global__ void k_prep_e(const float* __restrict__ emb, const float* __restrict__ inv_e,
                         unsigned short* __restrict__ Eh, unsigned short* __restrict__ El) {
    int g = blockIdx.x * 256 + threadIdx.x;
    float4 v = *(const float4*)(emb + (size_t)g * 4);
    float s = inv_e[g >> 6];
    v.x *= s; v.y *= s; v.z *= s; v.w *= s;
    ushort4 h, lo;
    h.x = f2bf(v.x); lo.x = f2bf(v.x - bf2f(h.x));
    h.y = f2bf(v.y); lo.y = f2bf(v.y - bf2f(h.y));
    h.z = f2bf(v.z); lo.z = f2bf(v.z - bf2f(h.z));
    h.w = f2bf(v.w); lo.w = f2bf(v.w - bf2f(h.w));
    *(ushort4*)(Eh + (size_t)g * 4) = h;
    *(ushort4*)(El + (size_t)g * 4) = lo;
}

// ---------------- MFMA bf16x2 3-pass score, 32x32x16, swizzled LDS ----------------
__launch_bounds__(256)
__global__ void k_score(const unsigned short* __restrict__ Zh, const unsigned short* __restrict__ Zl,
                        const unsigned short* __restrict__ Eh, const unsigned short* __restrict__ El,
                        f32x4* __restrict__ part) {
    // 4 arrays x 128 rows x 32 shorts = 16384 shorts = 32 KB
    __shared__ __align__(16) unsigned short lds[16384];
    const int t = threadIdx.x, l = t & 63, w = t >> 6;
    const int wm = w >> 1, wn = w & 1;          // 2x2 wave grid, wave tile 64x64
    const int m0 = blockIdx.y * BM;
    const int n0 = blockIdx.x * (BN * NT);
    const int l31 = l & 31, lh = l >> 5;

    // staging lane map: 16 rows x 4 chunks per 1-KB wave instr
    const int srow = l >> 2, sp = l & 3;

    float rv1 = -2e9f, rv2 = -2e9f; int ri1 = 0, ri2 = 0;

    for (int nt = 0; nt < NT; nt++) {
        const int nb = n0 + nt * BN;
        // wave w stages array w (0:Zh 1:Zl 2:Eh 3:El)
        const unsigned short* sbase =
            (w == 0) ? Zh + (size_t)m0 * DIM :
            (w == 1) ? Zl + (size_t)m0 * DIM :
            (w == 2) ? Eh + (size_t)nb * DIM :
                       El + (size_t)nb * DIM;

        f32x16 acc[2][2];
        #pragma unroll
        for (int i = 0; i < 2; i++)
            #pragma unroll
            for (int j = 0; j < 2; j++) acc[i][j] = (f32x16)0.f;

        for (int kc = 0; kc < DIM; kc += BK) {
            #pragma unroll
            for (int it = 0; it < 8; it++) {
                int r = it * 16 + srow;
                int c = sp ^ SWZ(r);
                async_copy16(sbase + (size_t)r * DIM + kc + c * 8,
                             &lds[w * 4096 + it * 512]);
            }
            __syncthreads();
            #pragma unroll
            for (int s = 0; s < 2; s++) {
                bf16x8 ah[2], al[2], bh[2], bl[2];
                #pragma unroll
                for (int i = 0; i < 2; i++) {
                    int r = wm * 64 + i * 32 + l31;
                    int c = 2 * s + lh;
                    int off = r * 32 + ((c ^ SWZ(r)) * 8);
                    ah[i] = *(const bf16x8*)&lds[off];
                    al[i] = *(const bf16x8*)&lds[4096 + off];
                }
                #pragma unroll
                for (int j = 0; j < 2; j++) {
                    int r = wn * 64 + j * 32 + l31;
                    int c = 2 * s + lh;
                    int off = r * 32 + ((c ^ SWZ(r)) * 8);
                    bh[j] = *(const bf16x8*)&lds[8192 + off];
                    bl[j] = *(const bf16x8*)&lds[12288 + off];
                }
                #pragma unroll
                for (int i = 0; i < 2; i++)
                    #pragma unroll
                    for (int j = 0; j < 2; j++) {
                        acc[i][j] = __builtin_amdgcn_mfma_f32_32x32x16_bf16(ah[i], bh[j], acc[i][j], 0, 0, 0);
                        acc[i][j] = __builtin_amdgcn_mfma_f32_32x32x16_bf16(ah[i], bl[j], acc[i][j], 0, 0, 0);
                        acc[i][j] = __builtin_amdgcn_mfma_f32_32x32x16_bf16(al[i], bh[j], acc[i][j], 0, 0, 0);
                    }
            }
            __syncthreads();
        }
        // ---- epilogue: per-row top-2 over this 128-col strip ----
        // C layout (32x32): col = l&31, row = (reg&3) + 8*(reg>>2) + 4*(l>>5)
        f32x4* red = (f32x4*)lds;                 // [128][2]
        #pragma unroll
        for (int i = 0; i < 2; i++) {
            #pragma unroll
            for (int reg = 0; reg < 16; reg++) {
                float V1 = -2e9f, V2 = -2e9f; int I1 = 0, I2 = 0;
                int c0 = nb + wn * 64 + l31;
                top2_merge(V1, I1, V2, I2, acc[i][0][reg], c0);
                top2_merge(V1, I1, V2, I2, acc[i][1][reg], c0 + 32);
                #pragma unroll
                for (int m = 1; m <= 16; m <<= 1) {
                    float w1 = __shfl_xor(V1, m); int j1 = __shfl_xor(I1, m);
                    float w2 = __shfl_xor(V2, m); int j2 = __shfl_xor(I2, m);
                    top2_merge(V1, I1, V2, I2, w1, j1);
                    top2_merge(V1, I1, V2, I2, w2, j2);
                }
                if (l31 == 0) {
                    int row = wm * 64 + i * 32 + (reg & 3) + 8 * (reg >> 2) + 4 * lh;
                    f32x4 e; e[0] = V1; e[1] = __int_as_float(I1);
                    e[2] = V2; e[3] = __int_as_float(I2);
                    red[row * 2 + wn] = e;
                }
            }
        }
        __syncthreads();
        if (t < BM) {
            #pragma unroll
            for (int s = 0; s < 2; s++) {
                f32x4 e = red[t * 2 + s];
                top2_merge(rv1, ri1, rv2, ri2, e[0], __float_as_int(e[1]));
                top2_merge(rv1, ri1, rv2, ri2, e[2], __float_as_int(e[3]));
            }
        }
        __syncthreads();
    }
    if (t < BM) {
        f32x4 e; e[0] = rv1; e[1] = __int_as_float(ri1);
        e[2] = rv2; e[3] = __int_as_float(ri2);
        part[(size_t)blockIdx.x * NROWS + m0 + t] = e;
    }
}

// ---------------- cross-split reduce + fp64 rescore of near-ties ----------------
__global__ void k_final(const f32x4* __restrict__ part, const float* __restrict__ z,
                        const float* __restrict__ emb, int* __restrict__ idx_ws,
                        float* __restrict__ out_idx) {
    int n = blockIdx.x * 256 + threadIdx.x;
    float V1 = -2e9f, V2 = -2e9f; int I1 = 0, I2 = 0;
    for (int s = 0; s < NSPL; s++) {
        f32x4 e = part[(size_t)s * NROWS + n];
        float cv1 = e[0]; int ci1 = __float_as_int(e[1]);
        float cv2 = e[2]; int ci2 = __float_as_int(e[3]);
        if (cv1 > V1 || (cv1 == V1 && ci1 < I1)) { V2 = V1; I2 = I1; V1 = cv1; I1 = ci1; }
        else if (cv1 > V2 || (cv1 == V2 && ci1 < I2)) { V2 = cv1; I2 = ci1; }
        if (cv2 > V2 || (cv2 == V2 && ci2 < I2)) { V2 = cv2; I2 = ci2; }
    }
    int best = I1;
    if (V1 - V2 < 1e-4f) {
        int b = n >> 10, hw = n & 1023;
        const float* zp = z + (size_t)b * DIM * HW + hw;
        const float* e1 = emb + (size_t)I1 * DIM;
        const float* e2 = emb + (size_t)I2 * DIM;
        double sz = 0, d1 = 0, d2 = 0, s1e = 0, s2e = 0;
        for (int c = 0; c < DIM; c++) {
            double zv = (double)zp[c * HW];
            double a1 = (double)e1[c], a2 = (double)e2[c];
            sz += zv * zv; d1 += zv * a1; d2 += zv * a2;
            s1e += a1 * a1; s2e += a2 * a2;
        }
        double q1 = d1 / (sqrt(sz) * sqrt(s1e));
        double q2 = d2 / (sqrt(sz) * sqrt(s2e));
        best = (q2 > q1 || (q2 == q1 && I2 < I1)) ? I2 : I1;
    }
    idx_ws[n] = best;
    out_idx[n] = (float)best;
}

// ---------------- gather z_q from bf16 hi/lo ----------------
__global__ void k_zq(const int* __restrict__ idx_ws, const unsigned short* __restrict__ Eh,
                     const unsigned short* __restrict__ El, float* __restrict__ zq) {
    int t = threadIdx.x;
    int n = blockIdx.x * 256 + t;
    int b = n >> 10, hw = n & 1023;
    int id = idx_ws[n];
    const unsigned short* rh = Eh + (size_t)id * DIM;
    const unsigned short* rl = El + (size_t)id * DIM;
    for (int c0 = 0; c0 < DIM; c0 += 8) {
        uint4 hh = *(const uint4*)(rh + c0);
        uint4 ll = *(const uint4*)(rl + c0);
        float v[8];
        v[0] = bf2f(hh.x & 0xffff) + bf2f(ll.x & 0xffff);
        v[1] = bf2f(hh.x >> 16)    + bf2f(ll.x >> 16);
        v[2] = bf2f(hh.y & 0xffff) + bf2f(ll.y & 0xffff);
        v[3] = bf2f(hh.y >> 16)    + bf2f(ll.y >> 16);
        v[4] = bf2f(hh.z & 0xffff) + bf2f(ll.z & 0xffff);
        v[5] = bf2f(hh.z >> 16)    + bf2f(ll.z >> 16);
        v[6] = bf2f(hh.w & 0xffff) + bf2f(ll.w & 0xffff);
        v[7] = bf2f(hh.w >> 16)    + bf2f(ll.w >> 16);
        #pragma unroll
        for (int j = 0; j < 8; j++)
            zq[(size_t)(b * DIM + c0 + j) * HW + hw] = v[j];
    }
}

extern "C" void kernel_launch(void* const* d_in, const int* in_sizes, int n_in,
                              void* d_out, int out_size, void* d_ws, size_t ws_size,
                              hipStream_t stream) {
    const float* z   = (const float*)d_in[0];
    const float* emb = (const float*)d_in[1];

    unsigned short* Zh = (unsigned short*)d_ws;           // 4 MB
    unsigned short* Zl = Zh + (size_t)NROWS * DIM;        // 4 MB
    unsigned short* Eh = Zl + (size_t)NROWS * DIM;        // 8 MB
    unsigned short* El = Eh + (size_t)NUM_E * DIM;        // 8 MB
    float* inv_e = (float*)(El + (size_t)NUM_E * DIM);
    float* inv_z = inv_e + NUM_E;
    int* idx_ws  = (int*)(inv_z + NROWS);

    float* zq      = (float*)d_out;
    float* out_idx = zq + (size_t)NROWS * DIM;
    // part lives in the z_q region of d_out: 64 * 8192 * 4 floats = 2,097,152 floats
    // (exactly the z_q size). k_final consumes it before k_zq overwrites with z_q.
    f32x4* part = (f32x4*)zq;

    k_inv_e  <<<NUM_E / 4, 256, 0, stream>>>(emb, inv_e);
    k_inv_z  <<<NROWS / 256, 256, 0, stream>>>(z, inv_z);
    k_prep_z <<<dim3(NROWS / 64, DIM / 64), 256, 0, stream>>>(z, inv_z, Zh, Zl);
    k_prep_e <<<NUM_E * DIM / 1024, 256, 0, stream>>>(emb, inv_e, Eh, El);
    k_score  <<<dim3(NSPL, NROWS / BM), 256, 0, stream>>>(Zh, Zl, Eh, El, part);
    k_final  <<<NROWS / 256, 256, 0, stream>>>(part, z, emb, idx_ws, out_idx);
    k_zq     <<<NROWS / 256, 256, 0, stream>>>(idx_ws, Eh, El, zq);
}

// Round 4
// 804.614 us; speedup vs baseline: 3.3496x; 3.3496x over previous
//
#include <hip/hip_runtime.h>

#define NUM_E   16384
#define DIM     256
#define NROWS   8192      // B*H*W
#define HW      1024      // H*W
#define BM      128
#define BN      128
#define NT      2         // col strips per block
#define BK      32
#define NCB     (NUM_E / (BN * NT))   // 64 col blocks
#define GATE    1e-4f

// 16-B chunk swizzle for staging (rows 0..127, chunks 0..3)
#define SWZ(r) ((((r) >> 1) ^ ((r) >> 3)) & 3)

typedef __bf16 bf16x8 __attribute__((ext_vector_type(8)));
typedef float  f32x4  __attribute__((ext_vector_type(4)));
typedef float  f32x16 __attribute__((ext_vector_type(16)));

__device__ __forceinline__ unsigned short f2bf(float x) {
    unsigned u = __float_as_uint(x);
    unsigned r = (u + 0x7fffu + ((u >> 16) & 1u)) >> 16;
    return (unsigned short)r;
}
__device__ __forceinline__ float bf2f(unsigned short h) {
    return __uint_as_float(((unsigned)h) << 16);
}
__device__ __forceinline__ void async_copy16(const void* g, void* l) {
    __builtin_amdgcn_global_load_lds(
        (const __attribute__((address_space(1))) unsigned int*)g,
        (__attribute__((address_space(3))) unsigned int*)l, 16, 0, 0);
}

// ---------------- inverse norms (+ fp64 code norms, + counter zero) ----------------
__global__ void k_inv_e(const float* __restrict__ emb, float* __restrict__ inv_e,
                        double* __restrict__ se2, int* __restrict__ cnt) {
    if (blockIdx.x == 0 && threadIdx.x == 0) *cnt = 0;
    int w = threadIdx.x >> 6, lane = threadIdx.x & 63;
    int k = blockIdx.x * 4 + w;
    float4 v = *(const float4*)(emb + (size_t)k * DIM + lane * 4);
    double s = (double)v.x*v.x + (double)v.y*v.y + (double)v.z*v.z + (double)v.w*v.w;
    for (int off = 32; off > 0; off >>= 1) s += __shfl_down(s, off);
    if (lane == 0) {
        se2[k] = fmax(s, 1e-24);
        inv_e[k] = 1.0f / fmaxf((float)sqrt(s), 1e-12f);
    }
}

__global__ void k_inv_z(const float* __restrict__ z, float* __restrict__ inv_z) {
    int n = blockIdx.x * 256 + threadIdx.x;
    int b = n >> 10, hw = n & 1023;
    const float* p = z + (size_t)b * DIM * HW + hw;
    float s = 0.f;
    #pragma unroll 8
    for (int c = 0; c < DIM; c++) { float v = p[c * HW]; s += v * v; }
    inv_z[n] = 1.0f / fmaxf(sqrtf(s), 1e-12f);
}

// ---------------- prep: normalized bf16 hi/lo splits ----------------
__global__ void k_prep_z(const float* __restrict__ z, const float* __restrict__ inv_z,
                         unsigned short* __restrict__ Zh, unsigned short* __restrict__ Zl) {
    __shared__ float T[64 * 68];
    int t = threadIdx.x;
    int n0 = blockIdx.x * 64, c0 = blockIdx.y * 64;
    int b = n0 >> 10, hw0 = n0 & 1023;
    #pragma unroll
    for (int i = 0; i < 4; i++) {
        int f = t + 256 * i;
        int cc = f >> 4, n4 = (f & 15) * 4;
        float4 v  = *(const float4*)(z + (size_t)(b * DIM + c0 + cc) * HW + hw0 + n4);
        float4 iv = *(const float4*)(inv_z + n0 + n4);
        v.x *= iv.x; v.y *= iv.y; v.z *= iv.z; v.w *= iv.w;
        *(float4*)&T[cc * 68 + n4] = v;
    }
    __syncthreads();
    #pragma unroll
    for (int i = 0; i < 4; i++) {
        int f = t + 256 * i;
        int nn = f >> 4, c4 = (f & 15) * 4;
        ushort4 h, lo;
        float x;
        x = T[(c4+0)*68 + nn]; h.x = f2bf(x); lo.x = f2bf(x - bf2f(h.x));
        x = T[(c4+1)*68 + nn]; h.y = f2bf(x); lo.y = f2bf(x - bf2f(h.y));
        x = T[(c4+2)*68 + nn]; h.z = f2bf(x); lo.z = f2bf(x - bf2f(h.z));
        x = T[(c4+3)*68 + nn]; h.w = f2bf(x); lo.w = f2bf(x - bf2f(h.w));
        size_t o = (size_t)(n0 + nn) * DIM + c0 + c4;
        *(ushort4*)(Zh + o) = h;
        *(ushort4*)(Zl + o) = lo;
    }
}

__global__ void k_prep_e(const float* __restrict__ emb, const float* __restrict__ inv_e,
                         unsigned short* __restrict__ Eh, unsigned short* __restrict__ El) {
    int g = blockIdx.x * 256 + threadIdx.x;
    float4 v = *(const float4*)(emb + (size_t)g * 4);
    float s = inv_e[g >> 6];
    v.x *= s; v.y *= s; v.z *= s; v.w *= s;
    ushort4 h, lo;
    h.x = f2bf(v.x); lo.x = f2bf(v.x - bf2f(h.x));
    h.y = f2bf(v.y); lo.y = f2bf(v.y - bf2f(h.y));
    h.z = f2bf(v.z); lo.z = f2bf(v.z - bf2f(h.z));
    h.w = f2bf(v.w); lo.w = f2bf(v.w - bf2f(h.w));
    *(ushort4*)(Eh + (size_t)g * 4) = h;
    *(ushort4*)(El + (size_t)g * 4) = lo;
}

// ---------------- MFMA bf16x2 3-pass score, spill-free LDS epilogue ----------------
__launch_bounds__(256, 3)
__global__ void k_score(const unsigned short* __restrict__ Zh, const unsigned short* __restrict__ Zl,
                        const unsigned short* __restrict__ Eh, const unsigned short* __restrict__ El,
                        f32x4* __restrict__ part) {
    // union: staging (4 arrays x 128 rows x 32 shorts = 32 KB) / epilogue f32 buf (33792 B)
    __shared__ __align__(16) float smem[8448];
    unsigned short* lds = (unsigned short*)smem;
    const int t = threadIdx.x, l = t & 63, w = t >> 6;
    const int wm = w >> 1, wn = w & 1;          // 2x2 wave grid, wave tile 64x64
    const int m0 = blockIdx.x * BM;
    const int n0 = blockIdx.y * (BN * NT);
    const int l31 = l & 31, lh = l >> 5;
    const int srow = l >> 2, sp = l & 3;        // staging lane map
    const int rl = t >> 2, q = t & 3;           // scan lane map (4 threads/row)

    // running per-row top2 at quad-leader threads (2 rows each: halves i=0,1)
    float VA1 = -2e9f, VA2 = -2e9f, VB1 = -2e9f, VB2 = -2e9f;
    int IA = 0, IB = 0;

    for (int nt = 0; nt < NT; nt++) {
        const int nb = n0 + nt * BN;
        const unsigned short* sbase =
            (w == 0) ? Zh + (size_t)m0 * DIM :
            (w == 1) ? Zl + (size_t)m0 * DIM :
            (w == 2) ? Eh + (size_t)nb * DIM :
                       El + (size_t)nb * DIM;

        f32x16 acc[2][2];
        #pragma unroll
        for (int i = 0; i < 2; i++)
            #pragma unroll
            for (int j = 0; j < 2; j++) acc[i][j] = (f32x16)0.f;

        for (int kc = 0; kc < DIM; kc += BK) {
            #pragma unroll
            for (int it = 0; it < 8; it++) {
                int r = it * 16 + srow;
                int c = sp ^ SWZ(r);
                async_copy16(sbase + (size_t)r * DIM + kc + c * 8,
                             &lds[w * 4096 + it * 512]);
            }
            __syncthreads();
            #pragma unroll
            for (int s = 0; s < 2; s++) {
                bf16x8 ah[2], al[2], bh[2], bl[2];
                #pragma unroll
                for (int i = 0; i < 2; i++) {
                    int r = wm * 64 + i * 32 + l31;
                    int c = 2 * s + lh;
                    int off = r * 32 + ((c ^ SWZ(r)) * 8);
                    ah[i] = *(const bf16x8*)&lds[off];
                    al[i] = *(const bf16x8*)&lds[4096 + off];
                }
                #pragma unroll
                for (int j = 0; j < 2; j++) {
                    int r = wn * 64 + j * 32 + l31;
                    int c = 2 * s + lh;
                    int off = r * 32 + ((c ^ SWZ(r)) * 8);
                    bh[j] = *(const bf16x8*)&lds[8192 + off];
                    bl[j] = *(const bf16x8*)&lds[12288 + off];
                }
                #pragma unroll
                for (int i = 0; i < 2; i++)
                    #pragma unroll
                    for (int j = 0; j < 2; j++) {
                        acc[i][j] = __builtin_amdgcn_mfma_f32_32x32x16_bf16(ah[i], bh[j], acc[i][j], 0, 0, 0);
                        acc[i][j] = __builtin_amdgcn_mfma_f32_32x32x16_bf16(ah[i], bl[j], acc[i][j], 0, 0, 0);
                        acc[i][j] = __builtin_amdgcn_mfma_f32_32x32x16_bf16(al[i], bh[j], acc[i][j], 0, 0, 0);
                    }
            }
            __syncthreads();
        }

        // ---- epilogue: two 64-row halves through LDS, branchless top-2 ----
        #pragma unroll
        for (int i = 0; i < 2; i++) {
            // dump acc[i] to swizzled f32 buffer: addr = row*132 + chunk*33 + (col&31)
            #pragma unroll
            for (int j = 0; j < 2; j++)
                #pragma unroll
                for (int reg = 0; reg < 16; reg++) {
                    int rr  = wm * 32 + (reg & 3) + 8 * (reg >> 2) + 4 * lh;
                    int col = wn * 64 + j * 32 + l31;
                    smem[rr * 132 + (col >> 5) * 33 + (col & 31)] = acc[i][j][reg];
                }
            __syncthreads();
            // scan: thread (rl,q) covers cols q*32..q*32+31 of local row rl
            float V1 = -2e9f, V2 = -2e9f; int I1 = 0;
            const float* p = &smem[rl * 132 + q * 33];
            #pragma unroll
            for (int u = 0; u < 32; u++) {
                float v = p[u];
                V2 = fmaxf(V2, fminf(v, V1));
                I1 = (v > V1) ? (nb + q * 32 + u) : I1;
                V1 = fmaxf(V1, v);
            }
            __syncthreads();   // buf free for next half / next strip staging
            // quad merge (lanes q,q+1 then q,q+2): other side is higher cols
            #pragma unroll
            for (int d = 1; d <= 2; d <<= 1) {
                float oV1 = __shfl_down(V1, d);
                float oV2 = __shfl_down(V2, d);
                int   oI1 = __shfl_down(I1, d);
                V2 = fmaxf(fmaxf(V2, oV2), fminf(oV1, V1));
                I1 = (oV1 > V1) ? oI1 : I1;
                V1 = fmaxf(V1, oV1);
            }
            if (i == 0) {
                VA2 = fmaxf(fmaxf(VA2, V2), fminf(V1, VA1));
                IA  = (V1 > VA1) ? I1 : IA;
                VA1 = fmaxf(VA1, V1);
            } else {
                VB2 = fmaxf(fmaxf(VB2, V2), fminf(V1, VB1));
                IB  = (V1 > VB1) ? I1 : IB;
                VB1 = fmaxf(VB1, V1);
            }
        }
    }
    if ((t & 3) == 0) {
        int rowA = (rl >> 5) * 64 + (rl & 31);   // half i=0
        int rowB = rowA + 32;                     // half i=1
        f32x4 ea; ea[0] = VA1; ea[1] = __int_as_float(IA); ea[2] = VA2; ea[3] = 0.f;
        part[(size_t)blockIdx.y * NROWS + m0 + rowA] = ea;
        f32x4 eb; eb[0] = VB1; eb[1] = __int_as_float(IB); eb[2] = VB2; eb[3] = 0.f;
        part[(size_t)blockIdx.y * NROWS + m0 + rowB] = eb;
    }
}

// ---------------- cross-block reduce + flag near-ties ----------------
__global__ void k_final(const f32x4* __restrict__ part, int* __restrict__ idx_ws,
                        float* __restrict__ out_idx, int* __restrict__ flags,
                        int* __restrict__ cnt) {
    int n = blockIdx.x * 256 + threadIdx.x;
    float V1 = -2e9f, V2 = -2e9f; int I1 = 0;
    for (int s = 0; s < NCB; s++) {
        f32x4 e = part[(size_t)s * NROWS + n];
        float v1 = e[0]; int i1 = __float_as_int(e[1]); float v2 = e[2];
        V2 = fmaxf(fmaxf(V2, v2), fminf(v1, V1));
        I1 = (v1 > V1) ? i1 : I1;
        V1 = fmaxf(V1, v1);
    }
    idx_ws[n] = I1;
    out_idx[n] = (float)I1;
    if (V1 - V2 < GATE) {
        int pos = atomicAdd(cnt, 1);
        flags[pos] = n;
    }
}

// ---------------- exact fp64 full-row rescan of flagged rows ----------------
__launch_bounds__(256)
__global__ void k_rescan(const int* __restrict__ flags, const int* __restrict__ cnt,
                         const float* __restrict__ z, const float* __restrict__ emb,
                         const double* __restrict__ se2,
                         int* __restrict__ idx_ws, float* __restrict__ out_idx) {
    __shared__ double zs[DIM];
    __shared__ double rv[256];
    __shared__ int    ri[256];
    int F = *cnt;
    for (int f = blockIdx.x; f < F; f += gridDim.x) {
        int n = flags[f];
        int b = n >> 10, hw = n & 1023;
        if (threadIdx.x < DIM)
            zs[threadIdx.x] = (double)z[(size_t)(b * DIM + threadIdx.x) * HW + hw];
        __syncthreads();
        double best = -2e18; int bi = 0;
        for (int k = threadIdx.x; k < NUM_E; k += 256) {
            const float* e = emb + (size_t)k * DIM;
            double d = 0.0;
            #pragma unroll 4
            for (int c = 0; c < DIM; c += 4) {
                float4 ev = *(const float4*)(e + c);
                d += zs[c] * (double)ev.x + zs[c+1] * (double)ev.y
                   + zs[c+2] * (double)ev.z + zs[c+3] * (double)ev.w;
            }
            double qv = d / sqrt(se2[k]);     // ||z|| constant per row
            if (qv > best) { best = qv; bi = k; }   // k ascending per thread
        }
        rv[threadIdx.x] = best; ri[threadIdx.x] = bi;
        __syncthreads();
        for (int s2 = 128; s2 > 0; s2 >>= 1) {
            if (threadIdx.x < s2) {
                double ov = rv[threadIdx.x + s2]; int oi = ri[threadIdx.x + s2];
                if (ov > rv[threadIdx.x] ||
                    (ov == rv[threadIdx.x] && oi < ri[threadIdx.x])) {
                    rv[threadIdx.x] = ov; ri[threadIdx.x] = oi;
                }
            }
            __syncthreads();
        }
        if (threadIdx.x == 0) { idx_ws[n] = ri[0]; out_idx[n] = (float)ri[0]; }
        __syncthreads();
    }
}

// ---------------- gather z_q = emb[idx] * inv_e[idx] (exact fp32) ----------------
__global__ void k_zq(const int* __restrict__ idx_ws, const float* __restrict__ emb,
                     const float* __restrict__ inv_e, float* __restrict__ zq) {
    int t = threadIdx.x;
    int n = blockIdx.x * 256 + t;
    int b = n >> 10, hw = n & 1023;
    int id = idx_ws[n];
    float s = inv_e[id];
    const float* er = emb + (size_t)id * DIM;
    for (int c0 = 0; c0 < DIM; c0 += 8) {
        float4 a  = *(const float4*)(er + c0);
        float4 bb = *(const float4*)(er + c0 + 4);
        float v[8] = {a.x*s, a.y*s, a.z*s, a.w*s, bb.x*s, bb.y*s, bb.z*s, bb.w*s};
        #pragma unroll
        for (int j = 0; j < 8; j++)
            zq[(size_t)(b * DIM + c0 + j) * HW + hw] = v[j];
    }
}

extern "C" void kernel_launch(void* const* d_in, const int* in_sizes, int n_in,
                              void* d_out, int out_size, void* d_ws, size_t ws_size,
                              hipStream_t stream) {
    const float* z   = (const float*)d_in[0];
    const float* emb = (const float*)d_in[1];

    unsigned short* Zh = (unsigned short*)d_ws;           // 4 MB
    unsigned short* Zl = Zh + (size_t)NROWS * DIM;        // 4 MB
    unsigned short* Eh = Zl + (size_t)NROWS * DIM;        // 8 MB
    unsigned short* El = Eh + (size_t)NUM_E * DIM;        // 8 MB
    float*  inv_e = (float*)(El + (size_t)NUM_E * DIM);   // 64 KB
    float*  inv_z = inv_e + NUM_E;                        // 32 KB
    int*    idx_ws = (int*)(inv_z + NROWS);               // 32 KB
    double* se2   = (double*)(idx_ws + NROWS);            // 128 KB
    int*    flags = (int*)(se2 + NUM_E);                  // 32 KB
    int*    cnt   = flags + NROWS;                        // 4 B

    float* zq      = (float*)d_out;
    float* out_idx = zq + (size_t)NROWS * DIM;
    // part aliases the z_q region (8 MB = 64*8192*16 B exactly);
    // consumed by k_final before k_zq overwrites it with z_q.
    f32x4* part = (f32x4*)zq;

    k_inv_e  <<<NUM_E / 4, 256, 0, stream>>>(emb, inv_e, se2, cnt);
    k_inv_z  <<<NROWS / 256, 256, 0, stream>>>(z, inv_z);
    k_prep_z <<<dim3(NROWS / 64, DIM / 64), 256, 0, stream>>>(z, inv_z, Zh, Zl);
    k_prep_e <<<NUM_E * DIM / 1024, 256, 0, stream>>>(emb, inv_e, Eh, El);
    k_score  <<<dim3(NROWS / BM, NCB), 256, 0, stream>>>(Zh, Zl, Eh, El, part);
    k_final  <<<NROWS / 256, 256, 0, stream>>>(part, idx_ws, out_idx, flags, cnt);
    k_rescan <<<256, 256, 0, stream>>>(flags, cnt, z, emb, se2, idx_ws, out_idx);
    k_zq     <<<NROWS / 256, 256, 0, stream>>>(idx_ws, emb, inv_e, zq);
}

// Round 5
// 464.047 us; speedup vs baseline: 5.8079x; 1.7339x over previous
//
#include <hip/hip_runtime.h>

#define NUM_E   16384
#define DIM     256
#define NROWS   8192      // B*H*W
#define HW      1024      // H*W
#define BM      128
#define BN      128
#define NT      2         // col strips per block
#define BK      32
#define NCB     (NUM_E / (BN * NT))   // 64 col blocks
#define GATE    1e-4f

// 16-B chunk swizzle for staging (rows 0..127, chunks 0..3)
#define SWZ(r) ((((r) >> 1) ^ ((r) >> 3)) & 3)

typedef __bf16 bf16x8 __attribute__((ext_vector_type(8)));
typedef float  f32x4  __attribute__((ext_vector_type(4)));
typedef float  f32x16 __attribute__((ext_vector_type(16)));

__device__ __forceinline__ unsigned short f2bf(float x) {
    unsigned u = __float_as_uint(x);
    unsigned r = (u + 0x7fffu + ((u >> 16) & 1u)) >> 16;
    return (unsigned short)r;
}
__device__ __forceinline__ float bf2f(unsigned short h) {
    return __uint_as_float(((unsigned)h) << 16);
}
__device__ __forceinline__ void async_copy16(const void* g, void* l) {
    __builtin_amdgcn_global_load_lds(
        (const __attribute__((address_space(1))) unsigned int*)g,
        (__attribute__((address_space(3))) unsigned int*)l, 16, 0, 0);
}

// ---------------- inverse norms (+ fp64 code norms, + counter zero) ----------------
__global__ void k_inv_e(const float* __restrict__ emb, float* __restrict__ inv_e,
                        double* __restrict__ se2, int* __restrict__ cnt) {
    if (blockIdx.x == 0 && threadIdx.x == 0) *cnt = 0;
    int w = threadIdx.x >> 6, lane = threadIdx.x & 63;
    int k = blockIdx.x * 4 + w;
    float4 v = *(const float4*)(emb + (size_t)k * DIM + lane * 4);
    double s = (double)v.x*v.x + (double)v.y*v.y + (double)v.z*v.z + (double)v.w*v.w;
    for (int off = 32; off > 0; off >>= 1) s += __shfl_down(s, off);
    if (lane == 0) {
        se2[k] = fmax(s, 1e-24);
        inv_e[k] = 1.0f / fmaxf((float)sqrt(s), 1e-12f);
    }
}

__global__ void k_inv_z(const float* __restrict__ z, float* __restrict__ inv_z) {
    int n = blockIdx.x * 256 + threadIdx.x;
    int b = n >> 10, hw = n & 1023;
    const float* p = z + (size_t)b * DIM * HW + hw;
    float s = 0.f;
    #pragma unroll 8
    for (int c = 0; c < DIM; c++) { float v = p[c * HW]; s += v * v; }
    inv_z[n] = 1.0f / fmaxf(sqrtf(s), 1e-12f);
}

// ---------------- prep: normalized bf16 hi/lo splits ----------------
__global__ void k_prep_z(const float* __restrict__ z, const float* __restrict__ inv_z,
                         unsigned short* __restrict__ Zh, unsigned short* __restrict__ Zl) {
    __shared__ float T[64 * 68];
    int t = threadIdx.x;
    int n0 = blockIdx.x * 64, c0 = blockIdx.y * 64;
    int b = n0 >> 10, hw0 = n0 & 1023;
    #pragma unroll
    for (int i = 0; i < 4; i++) {
        int f = t + 256 * i;
        int cc = f >> 4, n4 = (f & 15) * 4;
        float4 v  = *(const float4*)(z + (size_t)(b * DIM + c0 + cc) * HW + hw0 + n4);
        float4 iv = *(const float4*)(inv_z + n0 + n4);
        v.x *= iv.x; v.y *= iv.y; v.z *= iv.z; v.w *= iv.w;
        *(float4*)&T[cc * 68 + n4] = v;
    }
    __syncthreads();
    #pragma unroll
    for (int i = 0; i < 4; i++) {
        int f = t + 256 * i;
        int nn = f >> 4, c4 = (f & 15) * 4;
        ushort4 h, lo;
        float x;
        x = T[(c4+0)*68 + nn]; h.x = f2bf(x); lo.x = f2bf(x - bf2f(h.x));
        x = T[(c4+1)*68 + nn]; h.y = f2bf(x); lo.y = f2bf(x - bf2f(h.y));
        x = T[(c4+2)*68 + nn]; h.z = f2bf(x); lo.z = f2bf(x - bf2f(h.z));
        x = T[(c4+3)*68 + nn]; h.w = f2bf(x); lo.w = f2bf(x - bf2f(h.w));
        size_t o = (size_t)(n0 + nn) * DIM + c0 + c4;
        *(ushort4*)(Zh + o) = h;
        *(ushort4*)(Zl + o) = lo;
    }
}

__global__ void k_prep_e(const float* __restrict__ emb, const float* __restrict__ inv_e,
                         unsigned short* __restrict__ Eh, unsigned short* __restrict__ El) {
    int g = blockIdx.x * 256 + threadIdx.x;
    float4 v = *(const float4*)(emb + (size_t)g * 4);
    float s = inv_e[g >> 6];
    v.x *= s; v.y *= s; v.z *= s; v.w *= s;
    ushort4 h, lo;
    h.x = f2bf(v.x); lo.x = f2bf(v.x - bf2f(h.x));
    h.y = f2bf(v.y); lo.y = f2bf(v.y - bf2f(h.y));
    h.z = f2bf(v.z); lo.z = f2bf(v.z - bf2f(h.z));
    h.w = f2bf(v.w); lo.w = f2bf(v.w - bf2f(h.w));
    *(ushort4*)(Eh + (size_t)g * 4) = h;
    *(ushort4*)(El + (size_t)g * 4) = lo;
}

// ---------------- MFMA bf16x2 3-pass score, spill-free LDS epilogue ----------------
__launch_bounds__(256, 3)
__global__ void k_score(const unsigned short* __restrict__ Zh, const unsigned short* __restrict__ Zl,
                        const unsigned short* __restrict__ Eh, const unsigned short* __restrict__ El,
                        f32x4* __restrict__ part) {
    // union: staging (4 arrays x 128 rows x 32 shorts = 32 KB) / epilogue f32 buf (33792 B)
    __shared__ __align__(16) float smem[8448];
    unsigned short* lds = (unsigned short*)smem;
    const int t = threadIdx.x, l = t & 63, w = t >> 6;
    const int wm = w >> 1, wn = w & 1;          // 2x2 wave grid, wave tile 64x64
    const int m0 = blockIdx.x * BM;
    const int n0 = blockIdx.y * (BN * NT);
    const int l31 = l & 31, lh = l >> 5;
    const int srow = l >> 2, sp = l & 3;        // staging lane map
    const int rl = t >> 2, q = t & 3;           // scan lane map (4 threads/row)

    // running per-row top2 at quad-leader threads (2 rows each: halves i=0,1)
    float VA1 = -2e9f, VA2 = -2e9f, VB1 = -2e9f, VB2 = -2e9f;
    int IA = 0, IB = 0;

    for (int nt = 0; nt < NT; nt++) {
        const int nb = n0 + nt * BN;
        const unsigned short* sbase =
            (w == 0) ? Zh + (size_t)m0 * DIM :
            (w == 1) ? Zl + (size_t)m0 * DIM :
            (w == 2) ? Eh + (size_t)nb * DIM :
                       El + (size_t)nb * DIM;

        f32x16 acc[2][2];
        #pragma unroll
        for (int i = 0; i < 2; i++)
            #pragma unroll
            for (int j = 0; j < 2; j++) acc[i][j] = (f32x16)0.f;

        for (int kc = 0; kc < DIM; kc += BK) {
            #pragma unroll
            for (int it = 0; it < 8; it++) {
                int r = it * 16 + srow;
                int c = sp ^ SWZ(r);
                async_copy16(sbase + (size_t)r * DIM + kc + c * 8,
                             &lds[w * 4096 + it * 512]);
            }
            __syncthreads();
            #pragma unroll
            for (int s = 0; s < 2; s++) {
                bf16x8 ah[2], al[2], bh[2], bl[2];
                #pragma unroll
                for (int i = 0; i < 2; i++) {
                    int r = wm * 64 + i * 32 + l31;
                    int c = 2 * s + lh;
                    int off = r * 32 + ((c ^ SWZ(r)) * 8);
                    ah[i] = *(const bf16x8*)&lds[off];
                    al[i] = *(const bf16x8*)&lds[4096 + off];
                }
                #pragma unroll
                for (int j = 0; j < 2; j++) {
                    int r = wn * 64 + j * 32 + l31;
                    int c = 2 * s + lh;
                    int off = r * 32 + ((c ^ SWZ(r)) * 8);
                    bh[j] = *(const bf16x8*)&lds[8192 + off];
                    bl[j] = *(const bf16x8*)&lds[12288 + off];
                }
                #pragma unroll
                for (int i = 0; i < 2; i++)
                    #pragma unroll
                    for (int j = 0; j < 2; j++) {
                        acc[i][j] = __builtin_amdgcn_mfma_f32_32x32x16_bf16(ah[i], bh[j], acc[i][j], 0, 0, 0);
                        acc[i][j] = __builtin_amdgcn_mfma_f32_32x32x16_bf16(ah[i], bl[j], acc[i][j], 0, 0, 0);
                        acc[i][j] = __builtin_amdgcn_mfma_f32_32x32x16_bf16(al[i], bh[j], acc[i][j], 0, 0, 0);
                    }
            }
            __syncthreads();
        }

        // ---- epilogue: two 64-row halves through LDS, branchless top-2 ----
        #pragma unroll
        for (int i = 0; i < 2; i++) {
            #pragma unroll
            for (int j = 0; j < 2; j++)
                #pragma unroll
                for (int reg = 0; reg < 16; reg++) {
                    int rr  = wm * 32 + (reg & 3) + 8 * (reg >> 2) + 4 * lh;
                    int col = wn * 64 + j * 32 + l31;
                    smem[rr * 132 + (col >> 5) * 33 + (col & 31)] = acc[i][j][reg];
                }
            __syncthreads();
            float V1 = -2e9f, V2 = -2e9f; int I1 = 0;
            const float* p = &smem[rl * 132 + q * 33];
            #pragma unroll
            for (int u = 0; u < 32; u++) {
                float v = p[u];
                V2 = fmaxf(V2, fminf(v, V1));
                I1 = (v > V1) ? (nb + q * 32 + u) : I1;
                V1 = fmaxf(V1, v);
            }
            __syncthreads();
            #pragma unroll
            for (int d = 1; d <= 2; d <<= 1) {
                float oV1 = __shfl_down(V1, d);
                float oV2 = __shfl_down(V2, d);
                int   oI1 = __shfl_down(I1, d);
                V2 = fmaxf(fmaxf(V2, oV2), fminf(oV1, V1));
                I1 = (oV1 > V1) ? oI1 : I1;
                V1 = fmaxf(V1, oV1);
            }
            if (i == 0) {
                VA2 = fmaxf(fmaxf(VA2, V2), fminf(V1, VA1));
                IA  = (V1 > VA1) ? I1 : IA;
                VA1 = fmaxf(VA1, V1);
            } else {
                VB2 = fmaxf(fmaxf(VB2, V2), fminf(V1, VB1));
                IB  = (V1 > VB1) ? I1 : IB;
                VB1 = fmaxf(VB1, V1);
            }
        }
    }
    if ((t & 3) == 0) {
        int rowA = (rl >> 5) * 64 + (rl & 31);   // half i=0
        int rowB = rowA + 32;                     // half i=1
        f32x4 ea; ea[0] = VA1; ea[1] = __int_as_float(IA); ea[2] = VA2; ea[3] = 0.f;
        part[(size_t)blockIdx.y * NROWS + m0 + rowA] = ea;
        f32x4 eb; eb[0] = VB1; eb[1] = __int_as_float(IB); eb[2] = VB2; eb[3] = 0.f;
        part[(size_t)blockIdx.y * NROWS + m0 + rowB] = eb;
    }
}

// ---------------- cross-block reduce + flag near-ties ----------------
__global__ void k_final(const f32x4* __restrict__ part, int* __restrict__ idx_ws,
                        float* __restrict__ out_idx, int* __restrict__ flags,
                        int* __restrict__ cnt) {
    int n = blockIdx.x * 256 + threadIdx.x;
    float V1 = -2e9f, V2 = -2e9f; int I1 = 0;
    for (int s = 0; s < NCB; s++) {
        f32x4 e = part[(size_t)s * NROWS + n];
        float v1 = e[0]; int i1 = __float_as_int(e[1]); float v2 = e[2];
        V2 = fmaxf(fmaxf(V2, v2), fminf(v1, V1));
        I1 = (v1 > V1) ? i1 : I1;
        V1 = fmaxf(V1, v1);
    }
    idx_ws[n] = I1;
    out_idx[n] = (float)I1;
    if (V1 - V2 < GATE) {
        int pos = atomicAdd(cnt, 1);
        flags[pos] = n;
    }
}

// ---------------- exact fp64 rescan, parallel over (row, 256-code split) ----------------
// work item = f*64 + split; wave owns one code per pass (coalesced 1-KB row reads)
__launch_bounds__(256)
__global__ void k_rescan_part(const int* __restrict__ flags, const int* __restrict__ cnt,
                              const float* __restrict__ z, const float* __restrict__ emb,
                              const double* __restrict__ se2, double2* __restrict__ partial) {
    __shared__ double zs[DIM];
    __shared__ double wv[4];
    __shared__ int    wi[4];
    const int t = threadIdx.x, l = t & 63, w = t >> 6;
    const int W = (*cnt) * 64;
    for (int item = blockIdx.x; item < W; item += gridDim.x) {
        int f = item >> 6, split = item & 63;
        int n = flags[f];
        int b = n >> 10, hw = n & 1023;
        zs[t] = (double)z[(size_t)(b * DIM + t) * HW + hw];
        __syncthreads();
        double z0 = zs[l * 4], z1 = zs[l * 4 + 1], z2 = zs[l * 4 + 2], z3 = zs[l * 4 + 3];
        double best = -2e18; int bi = 0;
        int kbase = split * 256 + w * 64;
        for (int p = 0; p < 64; p++) {
            int k = kbase + p;
            float4 ev = *(const float4*)(emb + (size_t)k * DIM + l * 4);
            double d = z0 * (double)ev.x + z1 * (double)ev.y
                     + z2 * (double)ev.z + z3 * (double)ev.w;
            #pragma unroll
            for (int o = 32; o > 0; o >>= 1) d += __shfl_down(d, o);
            if (l == 0) {
                double qv = d / sqrt(se2[k]);
                if (qv > best) { best = qv; bi = k; }   // k ascending -> first index
            }
        }
        if (l == 0) { wv[w] = best; wi[w] = bi; }
        __syncthreads();
        if (t == 0) {
            double B = wv[0]; int BI = wi[0];
            #pragma unroll
            for (int x = 1; x < 4; x++)
                if (wv[x] > B || (wv[x] == B && wi[x] < BI)) { B = wv[x]; BI = wi[x]; }
            partial[item] = make_double2(B, (double)BI);
        }
        __syncthreads();
    }
}

__global__ void k_rescan_merge(const int* __restrict__ flags, const int* __restrict__ cnt,
                               const double2* __restrict__ partial,
                               int* __restrict__ idx_ws, float* __restrict__ out_idx) {
    const int F = *cnt;
    const int l = threadIdx.x & 63, w = threadIdx.x >> 6;
    for (int f = blockIdx.x * 4 + w; f < F; f += gridDim.x * 4) {
        double2 e = partial[(size_t)f * 64 + l];
        double v = e.x; int i = (int)e.y;
        #pragma unroll
        for (int o = 32; o > 0; o >>= 1) {
            double ov = __shfl_down(v, o);
            int    oi = __shfl_down(i, o);
            if (ov > v || (ov == v && oi < i)) { v = ov; i = oi; }
        }
        if (l == 0) { int n = flags[f]; idx_ws[n] = i; out_idx[n] = (float)i; }
    }
}

// ---------------- gather z_q = emb[idx] * inv_e[idx] (exact fp32) ----------------
__global__ void k_zq(const int* __restrict__ idx_ws, const float* __restrict__ emb,
                     const float* __restrict__ inv_e, float* __restrict__ zq) {
    int t = threadIdx.x;
    int n = blockIdx.x * 256 + t;
    int b = n >> 10, hw = n & 1023;
    int id = idx_ws[n];
    float s = inv_e[id];
    const float* er = emb + (size_t)id * DIM;
    for (int c0 = 0; c0 < DIM; c0 += 8) {
        float4 a  = *(const float4*)(er + c0);
        float4 bb = *(const float4*)(er + c0 + 4);
        float v[8] = {a.x*s, a.y*s, a.z*s, a.w*s, bb.x*s, bb.y*s, bb.z*s, bb.w*s};
        #pragma unroll
        for (int j = 0; j < 8; j++)
            zq[(size_t)(b * DIM + c0 + j) * HW + hw] = v[j];
    }
}

extern "C" void kernel_launch(void* const* d_in, const int* in_sizes, int n_in,
                              void* d_out, int out_size, void* d_ws, size_t ws_size,
                              hipStream_t stream) {
    const float* z   = (const float*)d_in[0];
    const float* emb = (const float*)d_in[1];

    unsigned short* Zh = (unsigned short*)d_ws;           // 4 MB
    unsigned short* Zl = Zh + (size_t)NROWS * DIM;        // 4 MB
    unsigned short* Eh = Zl + (size_t)NROWS * DIM;        // 8 MB
    unsigned short* El = Eh + (size_t)NUM_E * DIM;        // 8 MB
    float*  inv_e = (float*)(El + (size_t)NUM_E * DIM);   // 64 KB
    float*  inv_z = inv_e + NUM_E;                        // 32 KB
    int*    idx_ws = (int*)(inv_z + NROWS);               // 32 KB
    double* se2   = (double*)(idx_ws + NROWS);            // 128 KB
    int*    flags = (int*)(se2 + NUM_E);                  // 32 KB
    int*    cnt   = flags + NROWS;                        // 4 B

    float* zq      = (float*)d_out;
    float* out_idx = zq + (size_t)NROWS * DIM;
    // part (8 MB) aliases the z_q region; consumed by k_final, then the same
    // region is reused for rescan partials (8192*64*16 B = 8 MB), consumed by
    // k_rescan_merge, then finally overwritten with z_q by k_zq.
    f32x4*   part    = (f32x4*)zq;
    double2* partial = (double2*)zq;

    k_inv_e  <<<NUM_E / 4, 256, 0, stream>>>(emb, inv_e, se2, cnt);
    k_inv_z  <<<NROWS / 256, 256, 0, stream>>>(z, inv_z);
    k_prep_z <<<dim3(NROWS / 64, DIM / 64), 256, 0, stream>>>(z, inv_z, Zh, Zl);
    k_prep_e <<<NUM_E * DIM / 1024, 256, 0, stream>>>(emb, inv_e, Eh, El);
    k_score  <<<dim3(NROWS / BM, NCB), 256, 0, stream>>>(Zh, Zl, Eh, El, part);
    k_final  <<<NROWS / 256, 256, 0, stream>>>(part, idx_ws, out_idx, flags, cnt);
    k_rescan_part <<<2048, 256, 0, stream>>>(flags, cnt, z, emb, se2, partial);
    k_rescan_merge<<<64, 256, 0, stream>>>(flags, cnt, partial, idx_ws, out_idx);
    k_zq     <<<NROWS / 256, 256, 0, stream>>>(idx_ws, emb, inv_e, zq);
}

// Round 6
// 417.031 us; speedup vs baseline: 6.4626x; 1.1127x over previous
//
#include <hip/hip_runtime.h>

#define NUM_E   16384
#define DIM     256
#define NROWS   8192      // B*H*W
#define HW      1024      // H*W
#define BM      128
#define BN      256
#define BK      32
#define NCB     (NUM_E / BN)   // 64 col blocks
#define GATE    1e-4f

// 16-B chunk swizzle for staging (chunks 0..3 within a 32-short row)
#define SWZ(r) ((((r) >> 1) ^ ((r) >> 3)) & 3)

typedef __bf16 bf16x8 __attribute__((ext_vector_type(8)));
typedef float  f32x4  __attribute__((ext_vector_type(4)));
typedef float  f32x16 __attribute__((ext_vector_type(16)));

__device__ __forceinline__ unsigned short f2bf(float x) {
    unsigned u = __float_as_uint(x);
    unsigned r = (u + 0x7fffu + ((u >> 16) & 1u)) >> 16;
    return (unsigned short)r;
}
__device__ __forceinline__ float bf2f(unsigned short h) {
    return __uint_as_float(((unsigned)h) << 16);
}
__device__ __forceinline__ void async_copy16(const void* g, void* l) {
    __builtin_amdgcn_global_load_lds(
        (const __attribute__((address_space(1))) unsigned int*)g,
        (__attribute__((address_space(3))) unsigned int*)l, 16, 0, 0);
}

// ---------------- z row sum-of-squares partials (grid 32 x 16) ----------------
__global__ void k_sumz(const float* __restrict__ z, float* __restrict__ zpart,
                       int* __restrict__ cnt) {
    if (blockIdx.x == 0 && blockIdx.y == 0 && threadIdx.x == 0) *cnt = 0;
    int n = blockIdx.x * 256 + threadIdx.x;
    int b = n >> 10, hw = n & 1023;
    int cb = blockIdx.y;
    const float* p = z + (size_t)(b * DIM + cb * 16) * HW + hw;
    float s = 0.f;
    #pragma unroll
    for (int c = 0; c < 16; c++) { float v = p[c * HW]; s += v * v; }
    zpart[cb * NROWS + n] = s;
}

// ---------------- prep z: finalize inv_z in-block + bf16 hi/lo split ----------------
__global__ void k_prep_z(const float* __restrict__ z, const float* __restrict__ zpart,
                         unsigned short* __restrict__ Zh, unsigned short* __restrict__ Zl) {
    __shared__ float T[64 * 68];
    __shared__ __align__(16) float Tinv[64];
    int t = threadIdx.x;
    int n0 = blockIdx.x * 64, c0 = blockIdx.y * 64;
    int b = n0 >> 10, hw0 = n0 & 1023;
    if (t < 64) {
        float s = 0.f;
        #pragma unroll
        for (int cb = 0; cb < 16; cb++) s += zpart[cb * NROWS + n0 + t];
        Tinv[t] = 1.0f / fmaxf(sqrtf(s), 1e-12f);
    }
    __syncthreads();
    #pragma unroll
    for (int i = 0; i < 4; i++) {
        int f = t + 256 * i;
        int cc = f >> 4, n4 = (f & 15) * 4;
        float4 v  = *(const float4*)(z + (size_t)(b * DIM + c0 + cc) * HW + hw0 + n4);
        float4 iv = *(const float4*)&Tinv[n4];
        v.x *= iv.x; v.y *= iv.y; v.z *= iv.z; v.w *= iv.w;
        *(float4*)&T[cc * 68 + n4] = v;
    }
    __syncthreads();
    #pragma unroll
    for (int i = 0; i < 4; i++) {
        int f = t + 256 * i;
        int nn = f >> 4, c4 = (f & 15) * 4;
        ushort4 h, lo;
        float x;
        x = T[(c4+0)*68 + nn]; h.x = f2bf(x); lo.x = f2bf(x - bf2f(h.x));
        x = T[(c4+1)*68 + nn]; h.y = f2bf(x); lo.y = f2bf(x - bf2f(h.y));
        x = T[(c4+2)*68 + nn]; h.z = f2bf(x); lo.z = f2bf(x - bf2f(h.z));
        x = T[(c4+3)*68 + nn]; h.w = f2bf(x); lo.w = f2bf(x - bf2f(h.w));
        size_t o = (size_t)(n0 + nn) * DIM + c0 + c4;
        *(ushort4*)(Zh + o) = h;
        *(ushort4*)(Zl + o) = lo;
    }
}

// ---------------- prep e: fused fp64 norm + bf16 hi/lo split (4 rows/block) -------
__global__ void k_prep_e(const float* __restrict__ emb, float* __restrict__ inv_e,
                         double* __restrict__ se2,
                         unsigned short* __restrict__ Eh, unsigned short* __restrict__ El) {
    int wv = threadIdx.x >> 6, lane = threadIdx.x & 63;
    int k = blockIdx.x * 4 + wv;
    float4 v = *(const float4*)(emb + (size_t)k * DIM + lane * 4);
    double sq = (double)v.x*v.x + (double)v.y*v.y + (double)v.z*v.z + (double)v.w*v.w;
    for (int off = 32; off > 0; off >>= 1) sq += __shfl_down(sq, off);
    double tot = fmax(__shfl(sq, 0), 1e-24);
    if (lane == 0) { se2[k] = tot; inv_e[k] = 1.0f / fmaxf((float)sqrt(tot), 1e-12f); }
    float s = 1.0f / fmaxf((float)sqrt(tot), 1e-12f);
    v.x *= s; v.y *= s; v.z *= s; v.w *= s;
    ushort4 h, lo;
    h.x = f2bf(v.x); lo.x = f2bf(v.x - bf2f(h.x));
    h.y = f2bf(v.y); lo.y = f2bf(v.y - bf2f(h.y));
    h.z = f2bf(v.z); lo.z = f2bf(v.z - bf2f(h.z));
    h.w = f2bf(v.w); lo.w = f2bf(v.w - bf2f(h.w));
    size_t o = (size_t)k * DIM + lane * 4;
    *(ushort4*)(Eh + o) = h;
    *(ushort4*)(El + o) = lo;
}

// ---------------- MFMA bf16x2 3-pass score, 128x256 tile, 64x128 wave tile -------
__launch_bounds__(256, 2)
__global__ void k_score(const unsigned short* __restrict__ Zh, const unsigned short* __restrict__ Zl,
                        const unsigned short* __restrict__ Eh, const unsigned short* __restrict__ El,
                        f32x4* __restrict__ part) {
    // staging: Ah 4096 | Al 4096 | Bh 8192 | Bl 8192 shorts = 48 KB
    // epilogue union: 8448 f32 = 33792 B (fits)
    __shared__ __align__(16) unsigned short lds[24576];
    float* smem = (float*)lds;
    const int t = threadIdx.x, l = t & 63, w = t >> 6;
    const int wm = w >> 1, wn = w & 1;      // wave tile 64 x 128
    const int m0 = blockIdx.x * BM;
    const int nb = blockIdx.y * BN;
    const int l31 = l & 31, lh = l >> 5;
    const int sr = l >> 2, sp = l & 3;      // staging: 16 rows x 4 chunks / instr

    const unsigned short* gA0 = Zh + (size_t)m0 * DIM;
    const unsigned short* gA1 = Zl + (size_t)m0 * DIM;
    const unsigned short* gB0 = Eh + (size_t)nb * DIM;
    const unsigned short* gB1 = El + (size_t)nb * DIM;

    f32x16 acc[2][4];
    #pragma unroll
    for (int i = 0; i < 2; i++)
        #pragma unroll
        for (int j = 0; j < 4; j++) acc[i][j] = (f32x16)0.f;

    for (int kc = 0; kc < DIM; kc += BK) {
        #pragma unroll
        for (int h = 0; h < 2; h++) {       // A arrays: 8 subs over 4 waves x 2
            int sub = 4 * h + w;
            int r = sub * 16 + sr;
            int c = sp ^ SWZ(r);
            size_t go = (size_t)r * DIM + kc + c * 8;
            async_copy16(gA0 + go, &lds[sub * 512]);
            async_copy16(gA1 + go, &lds[4096 + sub * 512]);
        }
        #pragma unroll
        for (int h = 0; h < 4; h++) {       // B arrays: 16 subs over 4 waves x 4
            int sub = 4 * h + w;
            int r = sub * 16 + sr;
            int c = sp ^ SWZ(r);
            size_t go = (size_t)r * DIM + kc + c * 8;
            async_copy16(gB0 + go, &lds[8192 + sub * 512]);
            async_copy16(gB1 + go, &lds[16384 + sub * 512]);
        }
        __syncthreads();
        #pragma unroll
        for (int s = 0; s < 2; s++) {
            int c = 2 * s + lh;
            bf16x8 ah[2], al[2], bh[4], bl[4];
            #pragma unroll
            for (int i = 0; i < 2; i++) {
                int r = wm * 64 + i * 32 + l31;
                int off = r * 32 + ((c ^ SWZ(r)) * 8);
                ah[i] = *(const bf16x8*)&lds[off];
                al[i] = *(const bf16x8*)&lds[4096 + off];
            }
            #pragma unroll
            for (int j = 0; j < 4; j++) {
                int r = wn * 128 + j * 32 + l31;
                int off = r * 32 + ((c ^ SWZ(r)) * 8);
                bh[j] = *(const bf16x8*)&lds[8192 + off];
                bl[j] = *(const bf16x8*)&lds[16384 + off];
            }
            #pragma unroll
            for (int i = 0; i < 2; i++)
                #pragma unroll
                for (int j = 0; j < 4; j++) {
                    acc[i][j] = __builtin_amdgcn_mfma_f32_32x32x16_bf16(ah[i], bh[j], acc[i][j], 0, 0, 0);
                    acc[i][j] = __builtin_amdgcn_mfma_f32_32x32x16_bf16(ah[i], bl[j], acc[i][j], 0, 0, 0);
                    acc[i][j] = __builtin_amdgcn_mfma_f32_32x32x16_bf16(al[i], bh[j], acc[i][j], 0, 0, 0);
                }
        }
        __syncthreads();
    }

    // ---- epilogue: 2 row-halves x 2 col-halves through the LDS f32 buffer ----
    float VA1 = -2e9f, VA2 = -2e9f, VB1 = -2e9f, VB2 = -2e9f;
    int IA = 0, IB = 0;
    const int rl = t >> 2, q = t & 3;       // scan map: 4 threads/row x 32 cols
    #pragma unroll
    for (int i = 0; i < 2; i++) {
        #pragma unroll
        for (int jh = 0; jh < 2; jh++) {
            #pragma unroll
            for (int jj = 0; jj < 2; jj++) {
                int j = 2 * jh + jj;
                #pragma unroll
                for (int reg = 0; reg < 16; reg++) {
                    int rr = wm * 32 + (reg & 3) + 8 * (reg >> 2) + 4 * lh;
                    int cb = wn * 64 + jj * 32 + l31;
                    smem[rr * 132 + (cb >> 5) * 33 + (cb & 31)] = acc[i][j][reg];
                }
            }
            __syncthreads();
            float V1 = -2e9f, V2 = -2e9f; int I1 = 0;
            const float* p = &smem[rl * 132 + q * 33];
            int colbase = nb + (q >> 1) * 128 + jh * 64 + (q & 1) * 32;
            #pragma unroll
            for (int u = 0; u < 32; u++) {
                float v = p[u];
                V2 = fmaxf(V2, fminf(v, V1));
                I1 = (v > V1) ? (colbase + u) : I1;
                V1 = fmaxf(V1, v);
            }
            __syncthreads();
            #pragma unroll
            for (int d = 1; d <= 2; d <<= 1) {
                float oV1 = __shfl_down(V1, d);
                float oV2 = __shfl_down(V2, d);
                int   oI1 = __shfl_down(I1, d);
                V2 = fmaxf(fmaxf(V2, oV2), fminf(oV1, V1));
                I1 = (oV1 > V1) ? oI1 : I1;
                V1 = fmaxf(V1, oV1);
            }
            if (i == 0) {
                VA2 = fmaxf(fmaxf(VA2, V2), fminf(V1, VA1));
                IA  = (V1 > VA1) ? I1 : IA;
                VA1 = fmaxf(VA1, V1);
            } else {
                VB2 = fmaxf(fmaxf(VB2, V2), fminf(V1, VB1));
                IB  = (V1 > VB1) ? I1 : IB;
                VB1 = fmaxf(VB1, V1);
            }
        }
    }
    if ((t & 3) == 0) {
        int rowA = (rl >> 5) * 64 + (rl & 31);   // row-half i=0
        int rowB = rowA + 32;                     // row-half i=1
        f32x4 ea; ea[0] = VA1; ea[1] = __int_as_float(IA); ea[2] = VA2; ea[3] = 0.f;
        part[(size_t)blockIdx.y * NROWS + m0 + rowA] = ea;
        f32x4 eb; eb[0] = VB1; eb[1] = __int_as_float(IB); eb[2] = VB2; eb[3] = 0.f;
        part[(size_t)blockIdx.y * NROWS + m0 + rowB] = eb;
    }
}

// ---------------- cross-block reduce + flag near-ties (grid 256) ----------------
__global__ void k_final(const f32x4* __restrict__ part, int* __restrict__ idx_ws,
                        float* __restrict__ out_idx, int* __restrict__ flags,
                        int* __restrict__ cnt) {
    __shared__ f32x4 red[8][32];
    int nl = threadIdx.x & 31, sc = threadIdx.x >> 5;
    int n = blockIdx.x * 32 + nl;
    float V1 = -2e9f, V2 = -2e9f; int I1 = 0;
    for (int s = sc * 8; s < sc * 8 + 8; s++) {
        f32x4 e = part[(size_t)s * NROWS + n];
        float v1 = e[0]; int i1 = __float_as_int(e[1]); float v2 = e[2];
        V2 = fmaxf(fmaxf(V2, v2), fminf(v1, V1));
        I1 = (v1 > V1) ? i1 : I1;
        V1 = fmaxf(V1, v1);
    }
    f32x4 me; me[0] = V1; me[1] = __int_as_float(I1); me[2] = V2; me[3] = 0.f;
    red[sc][nl] = me;
    __syncthreads();
    if (threadIdx.x < 32) {
        float W1 = -2e9f, W2 = -2e9f; int J1 = 0;
        #pragma unroll
        for (int s2 = 0; s2 < 8; s2++) {
            f32x4 e = red[s2][threadIdx.x];
            float v1 = e[0]; int i1 = __float_as_int(e[1]); float v2 = e[2];
            W2 = fmaxf(fmaxf(W2, v2), fminf(v1, W1));
            J1 = (v1 > W1) ? i1 : J1;
            W1 = fmaxf(W1, v1);
        }
        int nn = blockIdx.x * 32 + threadIdx.x;
        idx_ws[nn] = J1;
        out_idx[nn] = (float)J1;
        if (W1 - W2 < GATE) {
            int pos = atomicAdd(cnt, 1);
            flags[pos] = nn;
        }
    }
}

// ---------------- exact fp64 rescan, parallel over (row, 256-code split) ----------
__launch_bounds__(256)
__global__ void k_rescan_part(const int* __restrict__ flags, const int* __restrict__ cnt,
                              const float* __restrict__ z, const float* __restrict__ emb,
                              const double* __restrict__ se2, double2* __restrict__ partial) {
    __shared__ double zs[DIM];
    __shared__ double wv[4];
    __shared__ int    wi[4];
    const int t = threadIdx.x, l = t & 63, w = t >> 6;
    const int W = (*cnt) * 64;
    for (int item = blockIdx.x; item < W; item += gridDim.x) {
        int f = item >> 6, split = item & 63;
        int n = flags[f];
        int b = n >> 10, hw = n & 1023;
        zs[t] = (double)z[(size_t)(b * DIM + t) * HW + hw];
        __syncthreads();
        double z0 = zs[l * 4], z1 = zs[l * 4 + 1], z2 = zs[l * 4 + 2], z3 = zs[l * 4 + 3];
        double best = -2e18; int bi = 0;
        int kbase = split * 256 + w * 64;
        for (int p = 0; p < 64; p++) {
            int k = kbase + p;
            float4 ev = *(const float4*)(emb + (size_t)k * DIM + l * 4);
            double d = z0 * (double)ev.x + z1 * (double)ev.y
                     + z2 * (double)ev.z + z3 * (double)ev.w;
            #pragma unroll
            for (int o = 32; o > 0; o >>= 1) d += __shfl_down(d, o);
            if (l == 0) {
                double qv = d / sqrt(se2[k]);
                if (qv > best) { best = qv; bi = k; }
            }
        }
        if (l == 0) { wv[w] = best; wi[w] = bi; }
        __syncthreads();
        if (t == 0) {
            double B = wv[0]; int BI = wi[0];
            #pragma unroll
            for (int x = 1; x < 4; x++)
                if (wv[x] > B || (wv[x] == B && wi[x] < BI)) { B = wv[x]; BI = wi[x]; }
            partial[item] = make_double2(B, (double)BI);
        }
        __syncthreads();
    }
}

__global__ void k_rescan_merge(const int* __restrict__ flags, const int* __restrict__ cnt,
                               const double2* __restrict__ partial,
                               int* __restrict__ idx_ws, float* __restrict__ out_idx) {
    const int F = *cnt;
    const int l = threadIdx.x & 63, w = threadIdx.x >> 6;
    for (int f = blockIdx.x * 4 + w; f < F; f += gridDim.x * 4) {
        double2 e = partial[(size_t)f * 64 + l];
        double v = e.x; int i = (int)e.y;
        #pragma unroll
        for (int o = 32; o > 0; o >>= 1) {
            double ov = __shfl_down(v, o);
            int    oi = __shfl_down(i, o);
            if (ov > v || (ov == v && oi < i)) { v = ov; i = oi; }
        }
        if (l == 0) { int n = flags[f]; idx_ws[n] = i; out_idx[n] = (float)i; }
    }
}

// ---------------- gather z_q = emb[idx] * inv_e[idx], grid (32, 8) ----------------
__global__ void k_zq(const int* __restrict__ idx_ws, const float* __restrict__ emb,
                     const float* __restrict__ inv_e, float* __restrict__ zq) {
    int t = threadIdx.x;
    int n = blockIdx.x * 256 + t;
    int b = n >> 10, hw = n & 1023;
    int c0 = blockIdx.y * 32;
    int id = idx_ws[n];
    float s = inv_e[id];
    const float* er = emb + (size_t)id * DIM;
    #pragma unroll
    for (int cc = 0; cc < 32; cc += 4) {
        float4 a = *(const float4*)(er + c0 + cc);
        zq[(size_t)(b * DIM + c0 + cc + 0) * HW + hw] = a.x * s;
        zq[(size_t)(b * DIM + c0 + cc + 1) * HW + hw] = a.y * s;
        zq[(size_t)(b * DIM + c0 + cc + 2) * HW + hw] = a.z * s;
        zq[(size_t)(b * DIM + c0 + cc + 3) * HW + hw] = a.w * s;
    }
}

extern "C" void kernel_launch(void* const* d_in, const int* in_sizes, int n_in,
                              void* d_out, int out_size, void* d_ws, size_t ws_size,
                              hipStream_t stream) {
    const float* z   = (const float*)d_in[0];
    const float* emb = (const float*)d_in[1];

    unsigned short* Zh = (unsigned short*)d_ws;           // 4 MB
    unsigned short* Zl = Zh + (size_t)NROWS * DIM;        // 4 MB
    unsigned short* Eh = Zl + (size_t)NROWS * DIM;        // 8 MB
    unsigned short* El = Eh + (size_t)NUM_E * DIM;        // 8 MB
    float*  inv_e = (float*)(El + (size_t)NUM_E * DIM);   // 64 KB
    float*  zpart = inv_e + NUM_E;                        // 512 KB (16 x 8192)
    int*    idx_ws = (int*)(zpart + 16 * NROWS);          // 32 KB
    double* se2   = (double*)(idx_ws + NROWS);            // 128 KB
    int*    flags = (int*)(se2 + NUM_E);                  // 32 KB
    int*    cnt   = flags + NROWS;                        // 4 B

    float* zq      = (float*)d_out;
    float* out_idx = zq + (size_t)NROWS * DIM;
    // part (8 MB) aliases the z_q region; consumed by k_final, then reused for
    // rescan partials, then finally overwritten with z_q by k_zq.
    f32x4*   part    = (f32x4*)zq;
    double2* partial = (double2*)zq;

    k_sumz   <<<dim3(NROWS / 256, 16), 256, 0, stream>>>(z, zpart, cnt);
    k_prep_z <<<dim3(NROWS / 64, DIM / 64), 256, 0, stream>>>(z, zpart, Zh, Zl);
    k_prep_e <<<NUM_E / 4, 256, 0, stream>>>(emb, inv_e, se2, Eh, El);
    k_score  <<<dim3(NROWS / BM, NCB), 256, 0, stream>>>(Zh, Zl, Eh, El, part);
    k_final  <<<NROWS / 32, 256, 0, stream>>>(part, idx_ws, out_idx, flags, cnt);
    k_rescan_part <<<2048, 256, 0, stream>>>(flags, cnt, z, emb, se2, partial);
    k_rescan_merge<<<64, 256, 0, stream>>>(flags, cnt, partial, idx_ws, out_idx);
    k_zq     <<<dim3(NROWS / 256, 8), 256, 0, stream>>>(idx_ws, emb, inv_e, zq);
}

// Round 7
// 303.800 us; speedup vs baseline: 8.8714x; 1.3727x over previous
//
#include <hip/hip_runtime.h>

#define NUM_E   16384
#define DIM     256
#define NROWS   8192      // B*H*W
#define HW      1024      // H*W
#define BM      128
#define BN      256
#define BK      32
#define NCB     (NUM_E / BN)   // 64 col blocks
#define GATE    1e-4f     // flag threshold (err bound 1.4e-5, 3.5x margin)
#define TAUC    1e-4f     // candidate-qualify threshold (>= 2*err)
#define EHID    4e-5      // hidden-code safety margin (>= err)

// 16-B chunk swizzle for staging (chunks 0..3 within a 32-short row)
#define SWZ(r) ((((r) >> 1) ^ ((r) >> 3)) & 3)

typedef __bf16 bf16x8 __attribute__((ext_vector_type(8)));
typedef float  f32x4  __attribute__((ext_vector_type(4)));
typedef float  f32x16 __attribute__((ext_vector_type(16)));

__device__ __forceinline__ unsigned short f2bf(float x) {
    unsigned u = __float_as_uint(x);
    unsigned r = (u + 0x7fffu + ((u >> 16) & 1u)) >> 16;
    return (unsigned short)r;
}
__device__ __forceinline__ float bf2f(unsigned short h) {
    return __uint_as_float(((unsigned)h) << 16);
}
__device__ __forceinline__ void async_copy16(const void* g, void* l) {
    __builtin_amdgcn_global_load_lds(
        (const __attribute__((address_space(1))) unsigned int*)g,
        (__attribute__((address_space(3))) unsigned int*)l, 16, 0, 0);
}

// ---------------- z row sum-of-squares partials (grid 32 x 16) ----------------
__global__ void k_sumz(const float* __restrict__ z, float* __restrict__ zpart,
                       int* __restrict__ cnt, int* __restrict__ cnt2) {
    if (blockIdx.x == 0 && blockIdx.y == 0 && threadIdx.x == 0) { *cnt = 0; *cnt2 = 0; }
    int n = blockIdx.x * 256 + threadIdx.x;
    int b = n >> 10, hw = n & 1023;
    int cb = blockIdx.y;
    const float* p = z + (size_t)(b * DIM + cb * 16) * HW + hw;
    float s = 0.f;
    #pragma unroll
    for (int c = 0; c < 16; c++) { float v = p[c * HW]; s += v * v; }
    zpart[cb * NROWS + n] = s;
}

// ---------------- prep z: finalize inv_z in-block + bf16 hi/lo split ----------------
__global__ void k_prep_z(const float* __restrict__ z, const float* __restrict__ zpart,
                         unsigned short* __restrict__ Zh, unsigned short* __restrict__ Zl) {
    __shared__ float T[64 * 68];
    __shared__ __align__(16) float Tinv[64];
    int t = threadIdx.x;
    int n0 = blockIdx.x * 64, c0 = blockIdx.y * 64;
    int b = n0 >> 10, hw0 = n0 & 1023;
    if (t < 64) {
        float s = 0.f;
        #pragma unroll
        for (int cb = 0; cb < 16; cb++) s += zpart[cb * NROWS + n0 + t];
        Tinv[t] = 1.0f / fmaxf(sqrtf(s), 1e-12f);
    }
    __syncthreads();
    #pragma unroll
    for (int i = 0; i < 4; i++) {
        int f = t + 256 * i;
        int cc = f >> 4, n4 = (f & 15) * 4;
        float4 v  = *(const float4*)(z + (size_t)(b * DIM + c0 + cc) * HW + hw0 + n4);
        float4 iv = *(const float4*)&Tinv[n4];
        v.x *= iv.x; v.y *= iv.y; v.z *= iv.z; v.w *= iv.w;
        *(float4*)&T[cc * 68 + n4] = v;
    }
    __syncthreads();
    #pragma unroll
    for (int i = 0; i < 4; i++) {
        int f = t + 256 * i;
        int nn = f >> 4, c4 = (f & 15) * 4;
        ushort4 h, lo;
        float x;
        x = T[(c4+0)*68 + nn]; h.x = f2bf(x); lo.x = f2bf(x - bf2f(h.x));
        x = T[(c4+1)*68 + nn]; h.y = f2bf(x); lo.y = f2bf(x - bf2f(h.y));
        x = T[(c4+2)*68 + nn]; h.z = f2bf(x); lo.z = f2bf(x - bf2f(h.z));
        x = T[(c4+3)*68 + nn]; h.w = f2bf(x); lo.w = f2bf(x - bf2f(h.w));
        size_t o = (size_t)(n0 + nn) * DIM + c0 + c4;
        *(ushort4*)(Zh + o) = h;
        *(ushort4*)(Zl + o) = lo;
    }
}

// ---------------- prep e: fused fp64 norm + bf16 hi/lo split (4 rows/block) -------
__global__ void k_prep_e(const float* __restrict__ emb, float* __restrict__ inv_e,
                         double* __restrict__ se2,
                         unsigned short* __restrict__ Eh, unsigned short* __restrict__ El) {
    int wv = threadIdx.x >> 6, lane = threadIdx.x & 63;
    int k = blockIdx.x * 4 + wv;
    float4 v = *(const float4*)(emb + (size_t)k * DIM + lane * 4);
    double sq = (double)v.x*v.x + (double)v.y*v.y + (double)v.z*v.z + (double)v.w*v.w;
    for (int off = 32; off > 0; off >>= 1) sq += __shfl_down(sq, off);
    double tot = fmax(__shfl(sq, 0), 1e-24);
    if (lane == 0) { se2[k] = tot; inv_e[k] = 1.0f / fmaxf((float)sqrt(tot), 1e-12f); }
    float s = 1.0f / fmaxf((float)sqrt(tot), 1e-12f);
    v.x *= s; v.y *= s; v.z *= s; v.w *= s;
    ushort4 h, lo;
    h.x = f2bf(v.x); lo.x = f2bf(v.x - bf2f(h.x));
    h.y = f2bf(v.y); lo.y = f2bf(v.y - bf2f(h.y));
    h.z = f2bf(v.z); lo.z = f2bf(v.z - bf2f(h.z));
    h.w = f2bf(v.w); lo.w = f2bf(v.w - bf2f(h.w));
    size_t o = (size_t)k * DIM + lane * 4;
    *(ushort4*)(Eh + o) = h;
    *(ushort4*)(El + o) = lo;
}

// ---------------- MFMA bf16x2 3-pass score, 128x256 tile, 64x128 wave tile -------
__launch_bounds__(256, 2)
__global__ void k_score(const unsigned short* __restrict__ Zh, const unsigned short* __restrict__ Zl,
                        const unsigned short* __restrict__ Eh, const unsigned short* __restrict__ El,
                        f32x4* __restrict__ part) {
    __shared__ __align__(16) unsigned short lds[24576];
    float* smem = (float*)lds;
    const int t = threadIdx.x, l = t & 63, w = t >> 6;
    const int wm = w >> 1, wn = w & 1;      // wave tile 64 x 128
    const int m0 = blockIdx.x * BM;
    const int nb = blockIdx.y * BN;
    const int l31 = l & 31, lh = l >> 5;
    const int sr = l >> 2, sp = l & 3;

    const unsigned short* gA0 = Zh + (size_t)m0 * DIM;
    const unsigned short* gA1 = Zl + (size_t)m0 * DIM;
    const unsigned short* gB0 = Eh + (size_t)nb * DIM;
    const unsigned short* gB1 = El + (size_t)nb * DIM;

    f32x16 acc[2][4];
    #pragma unroll
    for (int i = 0; i < 2; i++)
        #pragma unroll
        for (int j = 0; j < 4; j++) acc[i][j] = (f32x16)0.f;

    for (int kc = 0; kc < DIM; kc += BK) {
        #pragma unroll
        for (int h = 0; h < 2; h++) {
            int sub = 4 * h + w;
            int r = sub * 16 + sr;
            int c = sp ^ SWZ(r);
            size_t go = (size_t)r * DIM + kc + c * 8;
            async_copy16(gA0 + go, &lds[sub * 512]);
            async_copy16(gA1 + go, &lds[4096 + sub * 512]);
        }
        #pragma unroll
        for (int h = 0; h < 4; h++) {
            int sub = 4 * h + w;
            int r = sub * 16 + sr;
            int c = sp ^ SWZ(r);
            size_t go = (size_t)r * DIM + kc + c * 8;
            async_copy16(gB0 + go, &lds[8192 + sub * 512]);
            async_copy16(gB1 + go, &lds[16384 + sub * 512]);
        }
        __syncthreads();
        #pragma unroll
        for (int s = 0; s < 2; s++) {
            int c = 2 * s + lh;
            bf16x8 ah[2], al[2], bh[4], bl[4];
            #pragma unroll
            for (int i = 0; i < 2; i++) {
                int r = wm * 64 + i * 32 + l31;
                int off = r * 32 + ((c ^ SWZ(r)) * 8);
                ah[i] = *(const bf16x8*)&lds[off];
                al[i] = *(const bf16x8*)&lds[4096 + off];
            }
            #pragma unroll
            for (int j = 0; j < 4; j++) {
                int r = wn * 128 + j * 32 + l31;
                int off = r * 32 + ((c ^ SWZ(r)) * 8);
                bh[j] = *(const bf16x8*)&lds[8192 + off];
                bl[j] = *(const bf16x8*)&lds[16384 + off];
            }
            #pragma unroll
            for (int i = 0; i < 2; i++)
                #pragma unroll
                for (int j = 0; j < 4; j++) {
                    acc[i][j] = __builtin_amdgcn_mfma_f32_32x32x16_bf16(ah[i], bh[j], acc[i][j], 0, 0, 0);
                    acc[i][j] = __builtin_amdgcn_mfma_f32_32x32x16_bf16(ah[i], bl[j], acc[i][j], 0, 0, 0);
                    acc[i][j] = __builtin_amdgcn_mfma_f32_32x32x16_bf16(al[i], bh[j], acc[i][j], 0, 0, 0);
                }
        }
        __syncthreads();
    }

    // ---- epilogue: 2 row-halves x 2 col-halves through the LDS f32 buffer ----
    float VA1 = -2e9f, VA2 = -2e9f, VB1 = -2e9f, VB2 = -2e9f;
    int IA = 0, IB = 0;
    const int rl = t >> 2, q = t & 3;
    #pragma unroll
    for (int i = 0; i < 2; i++) {
        #pragma unroll
        for (int jh = 0; jh < 2; jh++) {
            #pragma unroll
            for (int jj = 0; jj < 2; jj++) {
                int j = 2 * jh + jj;
                #pragma unroll
                for (int reg = 0; reg < 16; reg++) {
                    int rr = wm * 32 + (reg & 3) + 8 * (reg >> 2) + 4 * lh;
                    int cb = wn * 64 + jj * 32 + l31;
                    smem[rr * 132 + (cb >> 5) * 33 + (cb & 31)] = acc[i][j][reg];
                }
            }
            __syncthreads();
            float V1 = -2e9f, V2 = -2e9f; int I1 = 0;
            const float* p = &smem[rl * 132 + q * 33];
            int colbase = nb + (q >> 1) * 128 + jh * 64 + (q & 1) * 32;
            #pragma unroll
            for (int u = 0; u < 32; u++) {
                float v = p[u];
                V2 = fmaxf(V2, fminf(v, V1));
                I1 = (v > V1) ? (colbase + u) : I1;
                V1 = fmaxf(V1, v);
            }
            __syncthreads();
            #pragma unroll
            for (int d = 1; d <= 2; d <<= 1) {
                float oV1 = __shfl_down(V1, d);
                float oV2 = __shfl_down(V2, d);
                int   oI1 = __shfl_down(I1, d);
                V2 = fmaxf(fmaxf(V2, oV2), fminf(oV1, V1));
                I1 = (oV1 > V1) ? oI1 : I1;
                V1 = fmaxf(V1, oV1);
            }
            if (i == 0) {
                VA2 = fmaxf(fmaxf(VA2, V2), fminf(V1, VA1));
                IA  = (V1 > VA1) ? I1 : IA;
                VA1 = fmaxf(VA1, V1);
            } else {
                VB2 = fmaxf(fmaxf(VB2, V2), fminf(V1, VB1));
                IB  = (V1 > VB1) ? I1 : IB;
                VB1 = fmaxf(VB1, V1);
            }
        }
    }
    if ((t & 3) == 0) {
        int rowA = (rl >> 5) * 64 + (rl & 31);
        int rowB = rowA + 32;
        f32x4 ea; ea[0] = VA1; ea[1] = __int_as_float(IA); ea[2] = VA2; ea[3] = 0.f;
        part[(size_t)blockIdx.y * NROWS + m0 + rowA] = ea;
        f32x4 eb; eb[0] = VB1; eb[1] = __int_as_float(IB); eb[2] = VB2; eb[3] = 0.f;
        part[(size_t)blockIdx.y * NROWS + m0 + rowB] = eb;
    }
}

// ---------------- reduce + flag near-ties + collect candidate columns ------------
__global__ void k_final(const f32x4* __restrict__ part, int* __restrict__ idx_ws,
                        float* __restrict__ out_idx, int* __restrict__ flags,
                        int* __restrict__ cnt, int* __restrict__ cand,
                        int* __restrict__ ccnt, float* __restrict__ v2q) {
    __shared__ f32x4 red[8][32];
    __shared__ float bcV1[32], bcV2[32];
    __shared__ int   lcc[32];
    __shared__ int   lcand[32][8];
    __shared__ float sv2[8][32];
    const int nl = threadIdx.x & 31, sc = threadIdx.x >> 5;
    const int n = blockIdx.x * 32 + nl;
    if (threadIdx.x < 32) lcc[threadIdx.x] = 0;
    // phase 1: top-2 reduce over 64 blocks
    float V1 = -2e9f, V2 = -2e9f; int I1 = 0;
    for (int s = sc * 8; s < sc * 8 + 8; s++) {
        f32x4 e = part[(size_t)s * NROWS + n];
        float v1 = e[0]; int i1 = __float_as_int(e[1]); float v2 = e[2];
        V2 = fmaxf(fmaxf(V2, v2), fminf(v1, V1));
        I1 = (v1 > V1) ? i1 : I1;
        V1 = fmaxf(V1, v1);
    }
    f32x4 me; me[0] = V1; me[1] = __int_as_float(I1); me[2] = V2; me[3] = 0.f;
    red[sc][nl] = me;
    __syncthreads();
    if (threadIdx.x < 32) {
        float W1 = -2e9f, W2 = -2e9f; int J1 = 0;
        #pragma unroll
        for (int s2 = 0; s2 < 8; s2++) {
            f32x4 e = red[s2][threadIdx.x];
            float v1 = e[0]; int i1 = __float_as_int(e[1]); float v2 = e[2];
            W2 = fmaxf(fmaxf(W2, v2), fminf(v1, W1));
            J1 = (v1 > W1) ? i1 : J1;
            W1 = fmaxf(W1, v1);
        }
        int nn = blockIdx.x * 32 + threadIdx.x;
        idx_ws[nn] = J1;
        out_idx[nn] = (float)J1;
        bcV1[threadIdx.x] = W1;
        bcV2[threadIdx.x] = W2;
    }
    __syncthreads();
    // phase 2: collect per-block top-1 cols within TAUC of the global max
    float thr = bcV1[nl] - TAUC;
    float lv2 = -2e9f;
    for (int s = sc * 8; s < sc * 8 + 8; s++) {
        f32x4 e = part[(size_t)s * NROWS + n];
        if (e[0] >= thr) {
            int pos = atomicAdd(&lcc[nl], 1);
            if (pos < 8) lcand[nl][pos] = __float_as_int(e[1]);
            lv2 = fmaxf(lv2, e[2]);
        }
    }
    sv2[sc][nl] = lv2;
    __syncthreads();
    if (threadIdx.x < 32) {
        int nn = blockIdx.x * 32 + threadIdx.x;
        float W1 = bcV1[threadIdx.x], W2 = bcV2[threadIdx.x];
        if (W1 - W2 < GATE) {
            float m = -2e9f;
            #pragma unroll
            for (int s2 = 0; s2 < 8; s2++) m = fmaxf(m, sv2[s2][threadIdx.x]);
            int p = atomicAdd(cnt, 1);
            flags[p] = nn;
            ccnt[nn] = lcc[threadIdx.x];
            v2q[nn] = m;
            #pragma unroll
            for (int j = 0; j < 8; j++) cand[nn * 8 + j] = lcand[threadIdx.x][j];
        }
    }
}

// ---------------- fp64 rescore of candidate columns (block per flagged row) ------
__launch_bounds__(256)
__global__ void k_rescan_cand(const int* __restrict__ flags, const int* __restrict__ cnt,
                              const int* __restrict__ cand, const int* __restrict__ ccnt,
                              const float* __restrict__ v2q,
                              const float* __restrict__ z, const float* __restrict__ emb,
                              const double* __restrict__ se2,
                              int* __restrict__ idx_ws, float* __restrict__ out_idx,
                              int* __restrict__ flags2, int* __restrict__ cnt2) {
    __shared__ double zs[DIM];
    __shared__ double wv[4];
    __shared__ int    wi[4];
    const int t = threadIdx.x, l = t & 63, w = t >> 6;
    const int F = *cnt;
    for (int f = blockIdx.x; f < F; f += gridDim.x) {
        int n = flags[f];
        int C = ccnt[n];
        int b = n >> 10, hw = n & 1023;
        __syncthreads();
        zs[t] = (double)z[(size_t)(b * DIM + t) * HW + hw];
        __syncthreads();
        double best = -2e18; int bi = 0x7fffffff;
        if (C <= 8) {
            double z0 = zs[l*4], z1 = zs[l*4+1], z2 = zs[l*4+2], z3 = zs[l*4+3];
            for (int cix = w; cix < C; cix += 4) {
                int k = cand[n * 8 + cix];
                float4 ev = *(const float4*)(emb + (size_t)k * DIM + l * 4);
                double d = z0 * (double)ev.x + z1 * (double)ev.y
                         + z2 * (double)ev.z + z3 * (double)ev.w;
                #pragma unroll
                for (int o = 32; o > 0; o >>= 1) d += __shfl_down(d, o);
                if (l == 0) {
                    double qv = d / sqrt(se2[k]);
                    if (qv > best || (qv == best && k < bi)) { best = qv; bi = k; }
                }
            }
        }
        if (l == 0) { wv[w] = best; wi[w] = bi; }
        __syncthreads();
        if (t == 0) {
            if (C > 8) {
                int p = atomicAdd(cnt2, 1); flags2[p] = n;
            } else {
                double B = wv[0]; int BI = wi[0];
                #pragma unroll
                for (int x = 1; x < 4; x++)
                    if (wv[x] > B || (wv[x] == B && wi[x] < BI)) { B = wv[x]; BI = wi[x]; }
                if ((double)v2q[n] >= B - EHID) {
                    int p = atomicAdd(cnt2, 1); flags2[p] = n;   // possible hidden code
                } else {
                    idx_ws[n] = BI; out_idx[n] = (float)BI;
                }
            }
        }
    }
}

// ---------------- rare fallback: full fp64 scan (parallel over row x split) ------
__launch_bounds__(256)
__global__ void k_fullscan_part(const int* __restrict__ flags2, const int* __restrict__ cnt2,
                                const float* __restrict__ z, const float* __restrict__ emb,
                                const double* __restrict__ se2, double2* __restrict__ partial) {
    __shared__ double zs[DIM];
    __shared__ double wv[4];
    __shared__ int    wi[4];
    const int t = threadIdx.x, l = t & 63, w = t >> 6;
    const int W = (*cnt2) * 64;
    for (int item = blockIdx.x; item < W; item += gridDim.x) {
        int f = item >> 6, split = item & 63;
        int n = flags2[f];
        int b = n >> 10, hw = n & 1023;
        __syncthreads();
        zs[t] = (double)z[(size_t)(b * DIM + t) * HW + hw];
        __syncthreads();
        double z0 = zs[l*4], z1 = zs[l*4+1], z2 = zs[l*4+2], z3 = zs[l*4+3];
        double best = -2e18; int bi = 0;
        int kbase = split * 256 + w * 64;
        for (int p = 0; p < 64; p++) {
            int k = kbase + p;
            float4 ev = *(const float4*)(emb + (size_t)k * DIM + l * 4);
            double d = z0 * (double)ev.x + z1 * (double)ev.y
                     + z2 * (double)ev.z + z3 * (double)ev.w;
            #pragma unroll
            for (int o = 32; o > 0; o >>= 1) d += __shfl_down(d, o);
            if (l == 0) {
                double qv = d / sqrt(se2[k]);
                if (qv > best) { best = qv; bi = k; }
            }
        }
        if (l == 0) { wv[w] = best; wi[w] = bi; }
        __syncthreads();
        if (t == 0) {
            double B = wv[0]; int BI = wi[0];
            #pragma unroll
            for (int x = 1; x < 4; x++)
                if (wv[x] > B || (wv[x] == B && wi[x] < BI)) { B = wv[x]; BI = wi[x]; }
            partial[item] = make_double2(B, (double)BI);
        }
        __syncthreads();
    }
}

__global__ void k_fullscan_merge(const int* __restrict__ flags2, const int* __restrict__ cnt2,
                                 const double2* __restrict__ partial,
                                 int* __restrict__ idx_ws, float* __restrict__ out_idx) {
    const int F = *cnt2;
    const int l = threadIdx.x & 63, w = threadIdx.x >> 6;
    for (int f = blockIdx.x * 4 + w; f < F; f += gridDim.x * 4) {
        double2 e = partial[(size_t)f * 64 + l];
        double v = e.x; int i = (int)e.y;
        #pragma unroll
        for (int o = 32; o > 0; o >>= 1) {
            double ov = __shfl_down(v, o);
            int    oi = __shfl_down(i, o);
            if (ov > v || (ov == v && oi < i)) { v = ov; i = oi; }
        }
        if (l == 0) { int n = flags2[f]; idx_ws[n] = i; out_idx[n] = (float)i; }
    }
}

// ---------------- gather z_q = emb[idx] * inv_e[idx], grid (32, 8) ----------------
__global__ void k_zq(const int* __restrict__ idx_ws, const float* __restrict__ emb,
                     const float* __restrict__ inv_e, float* __restrict__ zq) {
    int t = threadIdx.x;
    int n = blockIdx.x * 256 + t;
    int b = n >> 10, hw = n & 1023;
    int c0 = blockIdx.y * 32;
    int id = idx_ws[n];
    float s = inv_e[id];
    const float* er = emb + (size_t)id * DIM;
    #pragma unroll
    for (int cc = 0; cc < 32; cc += 4) {
        float4 a = *(const float4*)(er + c0 + cc);
        zq[(size_t)(b * DIM + c0 + cc + 0) * HW + hw] = a.x * s;
        zq[(size_t)(b * DIM + c0 + cc + 1) * HW + hw] = a.y * s;
        zq[(size_t)(b * DIM + c0 + cc + 2) * HW + hw] = a.z * s;
        zq[(size_t)(b * DIM + c0 + cc + 3) * HW + hw] = a.w * s;
    }
}

extern "C" void kernel_launch(void* const* d_in, const int* in_sizes, int n_in,
                              void* d_out, int out_size, void* d_ws, size_t ws_size,
                              hipStream_t stream) {
    const float* z   = (const float*)d_in[0];
    const float* emb = (const float*)d_in[1];

    unsigned short* Zh = (unsigned short*)d_ws;           // 4 MB
    unsigned short* Zl = Zh + (size_t)NROWS * DIM;        // 4 MB
    unsigned short* Eh = Zl + (size_t)NROWS * DIM;        // 8 MB
    unsigned short* El = Eh + (size_t)NUM_E * DIM;        // 8 MB
    float*  inv_e = (float*)(El + (size_t)NUM_E * DIM);   // 64 KB
    float*  zpart = inv_e + NUM_E;                        // 512 KB
    int*    idx_ws = (int*)(zpart + 16 * NROWS);          // 32 KB
    double* se2   = (double*)(idx_ws + NROWS);            // 128 KB
    int*    flags = (int*)(se2 + NUM_E);                  // 32 KB
    int*    flags2 = flags + NROWS;                       // 32 KB
    int*    cand  = flags2 + NROWS;                       // 256 KB
    int*    ccnt  = cand + NROWS * 8;                     // 32 KB
    float*  v2q   = (float*)(ccnt + NROWS);               // 32 KB
    int*    cnt   = (int*)(v2q + NROWS);                  // 4 B
    int*    cnt2  = cnt + 1;                              // 4 B

    float* zq      = (float*)d_out;
    float* out_idx = zq + (size_t)NROWS * DIM;
    // part (8 MB) aliases the z_q region; consumed by k_final/phase2, then the
    // same region is reused for fullscan partials, finally overwritten by k_zq.
    f32x4*   part    = (f32x4*)zq;
    double2* partial = (double2*)zq;

    k_sumz   <<<dim3(NROWS / 256, 16), 256, 0, stream>>>(z, zpart, cnt, cnt2);
    k_prep_z <<<dim3(NROWS / 64, DIM / 64), 256, 0, stream>>>(z, zpart, Zh, Zl);
    k_prep_e <<<NUM_E / 4, 256, 0, stream>>>(emb, inv_e, se2, Eh, El);
    k_score  <<<dim3(NROWS / BM, NCB), 256, 0, stream>>>(Zh, Zl, Eh, El, part);
    k_final  <<<NROWS / 32, 256, 0, stream>>>(part, idx_ws, out_idx, flags, cnt,
                                              cand, ccnt, v2q);
    k_rescan_cand  <<<1024, 256, 0, stream>>>(flags, cnt, cand, ccnt, v2q, z, emb,
                                              se2, idx_ws, out_idx, flags2, cnt2);
    k_fullscan_part<<<2048, 256, 0, stream>>>(flags2, cnt2, z, emb, se2, partial);
    k_fullscan_merge<<<64, 256, 0, stream>>>(flags2, cnt2, partial, idx_ws, out_idx);
    k_zq     <<<dim3(NROWS / 256, 8), 256, 0, stream>>>(idx_ws, emb, inv_e, zq);
}

// Round 8
// 257.446 us; speedup vs baseline: 10.4687x; 1.1801x over previous
//
#include <hip/hip_runtime.h>

#define NUM_E   16384
#define DIM     256
#define NROWS   8192      // B*H*W
#define HW      1024      // H*W
#define BM      128
#define BN      256
#define BK      32
#define NCB     (NUM_E / BN)   // 64 col blocks
#define GATE    1.2e-3f   // flag threshold (~6 sigma of 2e-4 pairwise err)
#define TAUC    1.2e-3f   // candidate-qualify threshold
#define EHID    1.2e-3    // hidden-code margin
#define MAXC    16

// 16-B chunk swizzle for staging (chunks 0..3 within a 32-short row)
#define SWZ(r) ((((r) >> 1) ^ ((r) >> 3)) & 3)

typedef __bf16 bf16x8 __attribute__((ext_vector_type(8)));
typedef float  f32x4  __attribute__((ext_vector_type(4)));
typedef float  f32x16 __attribute__((ext_vector_type(16)));

__device__ __forceinline__ unsigned short f2bf(float x) {
    unsigned u = __float_as_uint(x);
    unsigned r = (u + 0x7fffu + ((u >> 16) & 1u)) >> 16;
    return (unsigned short)r;
}
__device__ __forceinline__ float bf2f(unsigned short h) {
    return __uint_as_float(((unsigned)h) << 16);
}
__device__ __forceinline__ void async_copy16(const void* g, void* l) {
    __builtin_amdgcn_global_load_lds(
        (const __attribute__((address_space(1))) unsigned int*)g,
        (__attribute__((address_space(3))) unsigned int*)l, 16, 0, 0);
}

// ---------------- z row sum-of-squares partials (grid 32 x 16) ----------------
__global__ void k_sumz(const float* __restrict__ z, float* __restrict__ zpart) {
    int n = blockIdx.x * 256 + threadIdx.x;
    int b = n >> 10, hw = n & 1023;
    int cb = blockIdx.y;
    const float* p = z + (size_t)(b * DIM + cb * 16) * HW + hw;
    float s = 0.f;
    #pragma unroll
    for (int c = 0; c < 16; c++) { float v = p[c * HW]; s += v * v; }
    zpart[cb * NROWS + n] = s;
}

// ---------------- prep z: finalize inv_z in-block + bf16 hi/lo split -------------
__global__ void k_prep_z(const float* __restrict__ z, const float* __restrict__ zpart,
                         unsigned short* __restrict__ Zh, unsigned short* __restrict__ Zl) {
    __shared__ float T[64 * 68];
    __shared__ __align__(16) float Tinv[64];
    int t = threadIdx.x;
    int n0 = blockIdx.x * 64, c0 = blockIdx.y * 64;
    int b = n0 >> 10, hw0 = n0 & 1023;
    if (t < 64) {
        float s = 0.f;
        #pragma unroll
        for (int cb = 0; cb < 16; cb++) s += zpart[cb * NROWS + n0 + t];
        Tinv[t] = 1.0f / fmaxf(sqrtf(s), 1e-12f);
    }
    __syncthreads();
    #pragma unroll
    for (int i = 0; i < 4; i++) {
        int f = t + 256 * i;
        int cc = f >> 4, n4 = (f & 15) * 4;
        float4 v  = *(const float4*)(z + (size_t)(b * DIM + c0 + cc) * HW + hw0 + n4);
        float4 iv = *(const float4*)&Tinv[n4];
        v.x *= iv.x; v.y *= iv.y; v.z *= iv.z; v.w *= iv.w;
        *(float4*)&T[cc * 68 + n4] = v;
    }
    __syncthreads();
    #pragma unroll
    for (int i = 0; i < 4; i++) {
        int f = t + 256 * i;
        int nn = f >> 4, c4 = (f & 15) * 4;
        ushort4 h, lo;
        float x;
        x = T[(c4+0)*68 + nn]; h.x = f2bf(x); lo.x = f2bf(x - bf2f(h.x));
        x = T[(c4+1)*68 + nn]; h.y = f2bf(x); lo.y = f2bf(x - bf2f(h.y));
        x = T[(c4+2)*68 + nn]; h.z = f2bf(x); lo.z = f2bf(x - bf2f(h.z));
        x = T[(c4+3)*68 + nn]; h.w = f2bf(x); lo.w = f2bf(x - bf2f(h.w));
        size_t o = (size_t)(n0 + nn) * DIM + c0 + c4;
        *(ushort4*)(Zh + o) = h;
        *(ushort4*)(Zl + o) = lo;
    }
}

// ---------------- prep e: fp64 norm + bf16-hi only (El no longer needed) ---------
__global__ void k_prep_e(const float* __restrict__ emb, float* __restrict__ inv_e,
                         double* __restrict__ se2, unsigned short* __restrict__ Eh,
                         int* __restrict__ cnt, int* __restrict__ cnt2) {
    if (blockIdx.x == 0 && threadIdx.x == 0) { *cnt = 0; *cnt2 = 0; }
    int wv = threadIdx.x >> 6, lane = threadIdx.x & 63;
    int k = blockIdx.x * 4 + wv;
    float4 v = *(const float4*)(emb + (size_t)k * DIM + lane * 4);
    double sq = (double)v.x*v.x + (double)v.y*v.y + (double)v.z*v.z + (double)v.w*v.w;
    for (int off = 32; off > 0; off >>= 1) sq += __shfl_down(sq, off);
    double tot = fmax(__shfl(sq, 0), 1e-24);
    if (lane == 0) { se2[k] = tot; inv_e[k] = 1.0f / fmaxf((float)sqrt(tot), 1e-12f); }
    float s = 1.0f / fmaxf((float)sqrt(tot), 1e-12f);
    ushort4 h;
    h.x = f2bf(v.x * s); h.y = f2bf(v.y * s); h.z = f2bf(v.z * s); h.w = f2bf(v.w * s);
    *(ushort4*)(Eh + (size_t)k * DIM + lane * 4) = h;
}

// ---------------- MFMA bf16 2-pass score: (zh+zl)·eh, top-2 w/ indices ----------
__launch_bounds__(256, 2)
__global__ void k_score(const unsigned short* __restrict__ Zh, const unsigned short* __restrict__ Zl,
                        const unsigned short* __restrict__ Eh, f32x4* __restrict__ part) {
    // staging: Ah 4096 | Al 4096 | Bh 8192 shorts = 32 KB; epilogue f32 buf 33792 B
    __shared__ __align__(16) float smem[8448];
    unsigned short* lds = (unsigned short*)smem;
    const int t = threadIdx.x, l = t & 63, w = t >> 6;
    const int wm = w >> 1, wn = w & 1;      // wave tile 64 x 128
    const int m0 = blockIdx.x * BM;
    const int nb = blockIdx.y * BN;
    const int l31 = l & 31, lh = l >> 5;
    const int sr = l >> 2, sp = l & 3;

    const unsigned short* gA0 = Zh + (size_t)m0 * DIM;
    const unsigned short* gA1 = Zl + (size_t)m0 * DIM;
    const unsigned short* gB0 = Eh + (size_t)nb * DIM;

    f32x16 acc[2][4];
    #pragma unroll
    for (int i = 0; i < 2; i++)
        #pragma unroll
        for (int j = 0; j < 4; j++) acc[i][j] = (f32x16)0.f;

    for (int kc = 0; kc < DIM; kc += BK) {
        #pragma unroll
        for (int h = 0; h < 2; h++) {       // A: 8 subtiles x 2 arrays
            int sub = 4 * h + w;
            int r = sub * 16 + sr;
            int c = sp ^ SWZ(r);
            size_t go = (size_t)r * DIM + kc + c * 8;
            async_copy16(gA0 + go, &lds[sub * 512]);
            async_copy16(gA1 + go, &lds[4096 + sub * 512]);
        }
        #pragma unroll
        for (int h = 0; h < 4; h++) {       // B: 16 subtiles, hi only
            int sub = 4 * h + w;
            int r = sub * 16 + sr;
            int c = sp ^ SWZ(r);
            async_copy16(gB0 + (size_t)r * DIM + kc + c * 8, &lds[8192 + sub * 512]);
        }
        __syncthreads();
        #pragma unroll
        for (int s = 0; s < 2; s++) {
            int c = 2 * s + lh;
            bf16x8 ah[2], al[2], bh[4];
            #pragma unroll
            for (int i = 0; i < 2; i++) {
                int r = wm * 64 + i * 32 + l31;
                int off = r * 32 + ((c ^ SWZ(r)) * 8);
                ah[i] = *(const bf16x8*)&lds[off];
                al[i] = *(const bf16x8*)&lds[4096 + off];
            }
            #pragma unroll
            for (int j = 0; j < 4; j++) {
                int r = wn * 128 + j * 32 + l31;
                int off = r * 32 + ((c ^ SWZ(r)) * 8);
                bh[j] = *(const bf16x8*)&lds[8192 + off];
            }
            #pragma unroll
            for (int i = 0; i < 2; i++)
                #pragma unroll
                for (int j = 0; j < 4; j++) {
                    acc[i][j] = __builtin_amdgcn_mfma_f32_32x32x16_bf16(ah[i], bh[j], acc[i][j], 0, 0, 0);
                    acc[i][j] = __builtin_amdgcn_mfma_f32_32x32x16_bf16(al[i], bh[j], acc[i][j], 0, 0, 0);
                }
        }
        __syncthreads();
    }

    // ---- epilogue: LDS buffer scan, branchless top-2 WITH indices ----
    float VA1 = -2e9f, VA2 = -2e9f, VB1 = -2e9f, VB2 = -2e9f;
    int JA1 = 0, JA2 = 0, JB1 = 0, JB2 = 0;
    const int rl = t >> 2, q = t & 3;
    #pragma unroll
    for (int i = 0; i < 2; i++) {
        #pragma unroll
        for (int jh = 0; jh < 2; jh++) {
            #pragma unroll
            for (int jj = 0; jj < 2; jj++) {
                int j = 2 * jh + jj;
                #pragma unroll
                for (int reg = 0; reg < 16; reg++) {
                    int rr = wm * 32 + (reg & 3) + 8 * (reg >> 2) + 4 * lh;
                    int cb = wn * 64 + jj * 32 + l31;
                    smem[rr * 132 + (cb >> 5) * 33 + (cb & 31)] = acc[i][j][reg];
                }
            }
            __syncthreads();
            float V1 = -2e9f, V2 = -2e9f; int I1 = 0, I2 = 0;
            const float* p = &smem[rl * 132 + q * 33];
            int colbase = nb + (q >> 1) * 128 + jh * 64 + (q & 1) * 32;
            #pragma unroll
            for (int u = 0; u < 32; u++) {
                float v = p[u]; int c = colbase + u;
                bool g1 = v > V1, g2 = v > V2;
                I2 = g1 ? I1 : (g2 ? c : I2);
                V2 = g1 ? V1 : (g2 ? v : V2);
                I1 = g1 ? c : I1;
                V1 = g1 ? v : V1;
            }
            __syncthreads();
            #pragma unroll
            for (int d = 1; d <= 2; d <<= 1) {
                float oV1 = __shfl_down(V1, d), oV2 = __shfl_down(V2, d);
                int   oI1 = __shfl_down(I1, d), oI2 = __shfl_down(I2, d);
                bool o1 = oV1 > V1;
                float mn = o1 ? V1 : oV1; int mni = o1 ? I1 : oI1;
                V1 = o1 ? oV1 : V1; I1 = o1 ? oI1 : I1;
                bool s2 = oV2 > V2;
                float m2 = s2 ? oV2 : V2; int m2i = s2 ? oI2 : I2;
                bool c2 = m2 > mn;
                V2 = c2 ? m2 : mn; I2 = c2 ? m2i : mni;
            }
            if (i == 0) {
                bool o1 = V1 > VA1;
                float mn = o1 ? VA1 : V1; int mni = o1 ? JA1 : I1;
                VA1 = o1 ? V1 : VA1; JA1 = o1 ? I1 : JA1;
                bool s2 = V2 > VA2;
                float m2 = s2 ? V2 : VA2; int m2i = s2 ? I2 : JA2;
                bool c2 = m2 > mn;
                VA2 = c2 ? m2 : mn; JA2 = c2 ? m2i : mni;
            } else {
                bool o1 = V1 > VB1;
                float mn = o1 ? VB1 : V1; int mni = o1 ? JB1 : I1;
                VB1 = o1 ? V1 : VB1; JB1 = o1 ? I1 : JB1;
                bool s2 = V2 > VB2;
                float m2 = s2 ? V2 : VB2; int m2i = s2 ? I2 : JB2;
                bool c2 = m2 > mn;
                VB2 = c2 ? m2 : mn; JB2 = c2 ? m2i : mni;
            }
        }
    }
    if ((t & 3) == 0) {
        int rowA = (rl >> 5) * 64 + (rl & 31);
        int rowB = rowA + 32;
        f32x4 ea; ea[0] = VA1; ea[1] = __int_as_float(JA1);
        ea[2] = VA2; ea[3] = __int_as_float(JA2);
        part[(size_t)blockIdx.y * NROWS + m0 + rowA] = ea;
        f32x4 eb; eb[0] = VB1; eb[1] = __int_as_float(JB1);
        eb[2] = VB2; eb[3] = __int_as_float(JB2);
        part[(size_t)blockIdx.y * NROWS + m0 + rowB] = eb;
    }
}

// ---------------- reduce + flag near-ties + collect block-top-2 candidates -------
__global__ void k_final(const f32x4* __restrict__ part, int* __restrict__ idx_ws,
                        float* __restrict__ out_idx, int* __restrict__ flags,
                        int* __restrict__ cnt, int* __restrict__ cand,
                        int* __restrict__ ccnt, float* __restrict__ v2q) {
    __shared__ f32x4 red[8][32];
    __shared__ float bcV1[32], bcV2[32];
    __shared__ int   lcc[32];
    __shared__ int   lcand[32][MAXC];
    __shared__ float sv2[8][32];
    const int nl = threadIdx.x & 31, sc = threadIdx.x >> 5;
    const int n = blockIdx.x * 32 + nl;
    if (threadIdx.x < 32) lcc[threadIdx.x] = 0;
    // phase 1: global top-2 values
    float V1 = -2e9f, V2 = -2e9f; int I1 = 0;
    for (int s = sc * 8; s < sc * 8 + 8; s++) {
        f32x4 e = part[(size_t)s * NROWS + n];
        float v1 = e[0]; int i1 = __float_as_int(e[1]); float v2 = e[2];
        V2 = fmaxf(fmaxf(V2, v2), fminf(v1, V1));
        I1 = (v1 > V1) ? i1 : I1;
        V1 = fmaxf(V1, v1);
    }
    f32x4 me; me[0] = V1; me[1] = __int_as_float(I1); me[2] = V2; me[3] = 0.f;
    red[sc][nl] = me;
    __syncthreads();
    if (threadIdx.x < 32) {
        float W1 = -2e9f, W2 = -2e9f; int J1 = 0;
        #pragma unroll
        for (int s2 = 0; s2 < 8; s2++) {
            f32x4 e = red[s2][threadIdx.x];
            float v1 = e[0]; int i1 = __float_as_int(e[1]); float v2 = e[2];
            W2 = fmaxf(fmaxf(W2, v2), fminf(v1, W1));
            J1 = (v1 > W1) ? i1 : J1;
            W1 = fmaxf(W1, v1);
        }
        int nn = blockIdx.x * 32 + threadIdx.x;
        idx_ws[nn] = J1;
        out_idx[nn] = (float)J1;
        bcV1[threadIdx.x] = W1;
        bcV2[threadIdx.x] = W2;
    }
    __syncthreads();
    // phase 2: collect both top-2 indices of each block whose top-1 >= W1-TAUC
    float thr = bcV1[nl] - TAUC;
    float lv2 = -2e9f;
    for (int s = sc * 8; s < sc * 8 + 8; s++) {
        f32x4 e = part[(size_t)s * NROWS + n];
        if (e[0] >= thr) {
            int pos = atomicAdd(&lcc[nl], 2);
            if (pos < MAXC)     lcand[nl][pos]     = __float_as_int(e[1]);
            if (pos + 1 < MAXC) lcand[nl][pos + 1] = __float_as_int(e[3]);
            lv2 = fmaxf(lv2, e[2]);
        }
    }
    sv2[sc][nl] = lv2;
    __syncthreads();
    if (threadIdx.x < 32) {
        int nn = blockIdx.x * 32 + threadIdx.x;
        float W1 = bcV1[threadIdx.x], W2 = bcV2[threadIdx.x];
        if (W1 - W2 < GATE) {
            float m = -2e9f;
            #pragma unroll
            for (int s2 = 0; s2 < 8; s2++) m = fmaxf(m, sv2[s2][threadIdx.x]);
            int p = atomicAdd(cnt, 1);
            flags[p] = nn;
            ccnt[nn] = lcc[threadIdx.x];
            v2q[nn] = m;
            #pragma unroll
            for (int j = 0; j < MAXC; j++) cand[nn * MAXC + j] = lcand[threadIdx.x][j];
        }
    }
}

// ---------------- fp64 rescore of candidate columns (block per flagged row) ------
__launch_bounds__(256)
__global__ void k_rescan_cand(const int* __restrict__ flags, const int* __restrict__ cnt,
                              const int* __restrict__ cand, const int* __restrict__ ccnt,
                              const float* __restrict__ v2q,
                              const float* __restrict__ z, const float* __restrict__ emb,
                              const double* __restrict__ se2,
                              int* __restrict__ idx_ws, float* __restrict__ out_idx,
                              int* __restrict__ flags2, int* __restrict__ cnt2) {
    __shared__ double zs[DIM];
    __shared__ double wv[4];
    __shared__ int    wi[4];
    const int t = threadIdx.x, l = t & 63, w = t >> 6;
    const int F = *cnt;
    for (int f = blockIdx.x; f < F; f += gridDim.x) {
        int n = flags[f];
        int C = ccnt[n];
        int b = n >> 10, hw = n & 1023;
        __syncthreads();
        zs[t] = (double)z[(size_t)(b * DIM + t) * HW + hw];
        __syncthreads();
        double best = -2e18; int bi = 0x7fffffff;
        if (C <= MAXC) {
            double z0 = zs[l*4], z1 = zs[l*4+1], z2 = zs[l*4+2], z3 = zs[l*4+3];
            for (int cix = w; cix < C; cix += 4) {
                int k = cand[n * MAXC + cix];
                float4 ev = *(const float4*)(emb + (size_t)k * DIM + l * 4);
                double d = z0 * (double)ev.x + z1 * (double)ev.y
                         + z2 * (double)ev.z + z3 * (double)ev.w;
                #pragma unroll
                for (int o = 32; o > 0; o >>= 1) d += __shfl_down(d, o);
                if (l == 0) {
                    double qv = d / sqrt(se2[k]);
                    if (qv > best || (qv == best && k < bi)) { best = qv; bi = k; }
                }
            }
        }
        if (l == 0) { wv[w] = best; wi[w] = bi; }
        __syncthreads();
        if (t == 0) {
            if (C > MAXC) {
                int p = atomicAdd(cnt2, 1); flags2[p] = n;
            } else {
                double B = wv[0]; int BI = wi[0];
                #pragma unroll
                for (int x = 1; x < 4; x++)
                    if (wv[x] > B || (wv[x] == B && wi[x] < BI)) { B = wv[x]; BI = wi[x]; }
                if ((double)v2q[n] >= B - EHID) {
                    int p = atomicAdd(cnt2, 1); flags2[p] = n;   // possible hidden code
                } else {
                    idx_ws[n] = BI; out_idx[n] = (float)BI;
                }
            }
        }
    }
}

// ---------------- rare fallback: full fp64 scan (parallel over row x split) ------
__launch_bounds__(256)
__global__ void k_fullscan_part(const int* __restrict__ flags2, const int* __restrict__ cnt2,
                                const float* __restrict__ z, const float* __restrict__ emb,
                                const double* __restrict__ se2, double2* __restrict__ partial) {
    __shared__ double zs[DIM];
    __shared__ double wv[4];
    __shared__ int    wi[4];
    const int t = threadIdx.x, l = t & 63, w = t >> 6;
    const int W = (*cnt2) * 64;
    for (int item = blockIdx.x; item < W; item += gridDim.x) {
        int f = item >> 6, split = item & 63;
        int n = flags2[f];
        int b = n >> 10, hw = n & 1023;
        __syncthreads();
        zs[t] = (double)z[(size_t)(b * DIM + t) * HW + hw];
        __syncthreads();
        double z0 = zs[l*4], z1 = zs[l*4+1], z2 = zs[l*4+2], z3 = zs[l*4+3];
        double best = -2e18; int bi = 0;
        int kbase = split * 256 + w * 64;
        for (int p = 0; p < 64; p++) {
            int k = kbase + p;
            float4 ev = *(const float4*)(emb + (size_t)k * DIM + l * 4);
            double d = z0 * (double)ev.x + z1 * (double)ev.y
                     + z2 * (double)ev.z + z3 * (double)ev.w;
            #pragma unroll
            for (int o = 32; o > 0; o >>= 1) d += __shfl_down(d, o);
            if (l == 0) {
                double qv = d / sqrt(se2[k]);
                if (qv > best) { best = qv; bi = k; }
            }
        }
        if (l == 0) { wv[w] = best; wi[w] = bi; }
        __syncthreads();
        if (t == 0) {
            double B = wv[0]; int BI = wi[0];
            #pragma unroll
            for (int x = 1; x < 4; x++)
                if (wv[x] > B || (wv[x] == B && wi[x] < BI)) { B = wv[x]; BI = wi[x]; }
            partial[item] = make_double2(B, (double)BI);
        }
        __syncthreads();
    }
}

__global__ void k_fullscan_merge(const int* __restrict__ flags2, const int* __restrict__ cnt2,
                                 const double2* __restrict__ partial,
                                 int* __restrict__ idx_ws, float* __restrict__ out_idx) {
    const int F = *cnt2;
    const int l = threadIdx.x & 63, w = threadIdx.x >> 6;
    for (int f = blockIdx.x * 4 + w; f < F; f += gridDim.x * 4) {
        double2 e = partial[(size_t)f * 64 + l];
        double v = e.x; int i = (int)e.y;
        #pragma unroll
        for (int o = 32; o > 0; o >>= 1) {
            double ov = __shfl_down(v, o);
            int    oi = __shfl_down(i, o);
            if (ov > v || (ov == v && oi < i)) { v = ov; i = oi; }
        }
        if (l == 0) { int n = flags2[f]; idx_ws[n] = i; out_idx[n] = (float)i; }
    }
}

// ---------------- gather z_q = emb[idx] * inv_e[idx], grid (32, 8) ----------------
__global__ void k_zq(const int* __restrict__ idx_ws, const float* __restrict__ emb,
                     const float* __restrict__ inv_e, float* __restrict__ zq) {
    int t = threadIdx.x;
    int n = blockIdx.x * 256 + t;
    int b = n >> 10, hw = n & 1023;
    int c0 = blockIdx.y * 32;
    int id = idx_ws[n];
    float s = inv_e[id];
    const float* er = emb + (size_t)id * DIM;
    #pragma unroll
    for (int cc = 0; cc < 32; cc += 4) {
        float4 a = *(const float4*)(er + c0 + cc);
        zq[(size_t)(b * DIM + c0 + cc + 0) * HW + hw] = a.x * s;
        zq[(size_t)(b * DIM + c0 + cc + 1) * HW + hw] = a.y * s;
        zq[(size_t)(b * DIM + c0 + cc + 2) * HW + hw] = a.z * s;
        zq[(size_t)(b * DIM + c0 + cc + 3) * HW + hw] = a.w * s;
    }
}

extern "C" void kernel_launch(void* const* d_in, const int* in_sizes, int n_in,
                              void* d_out, int out_size, void* d_ws, size_t ws_size,
                              hipStream_t stream) {
    const float* z   = (const float*)d_in[0];
    const float* emb = (const float*)d_in[1];

    unsigned short* Zh = (unsigned short*)d_ws;           // 4 MB
    unsigned short* Zl = Zh + (size_t)NROWS * DIM;        // 4 MB
    unsigned short* Eh = Zl + (size_t)NROWS * DIM;        // 8 MB
    float*  inv_e = (float*)(Eh + (size_t)NUM_E * DIM);   // 64 KB
    float*  zpart = inv_e + NUM_E;                        // 512 KB
    int*    idx_ws = (int*)(zpart + 16 * NROWS);          // 32 KB
    double* se2   = (double*)(idx_ws + NROWS);            // 128 KB
    int*    flags = (int*)(se2 + NUM_E);                  // 32 KB
    int*    flags2 = flags + NROWS;                       // 32 KB
    int*    cand  = flags2 + NROWS;                       // 512 KB (16/row)
    int*    ccnt  = cand + NROWS * MAXC;                  // 32 KB
    float*  v2q   = (float*)(ccnt + NROWS);               // 32 KB
    int*    cnt   = (int*)(v2q + NROWS);                  // 4 B
    int*    cnt2  = cnt + 1;                              // 4 B

    float* zq      = (float*)d_out;
    float* out_idx = zq + (size_t)NROWS * DIM;
    // part (8 MB) aliases the z_q region; consumed by k_final, then reused for
    // fullscan partials, finally overwritten with z_q by k_zq.
    f32x4*   part    = (f32x4*)zq;
    double2* partial = (double2*)zq;

    k_sumz   <<<dim3(NROWS / 256, 16), 256, 0, stream>>>(z, zpart);
    k_prep_z <<<dim3(NROWS / 64, DIM / 64), 256, 0, stream>>>(z, zpart, Zh, Zl);
    k_prep_e <<<NUM_E / 4, 256, 0, stream>>>(emb, inv_e, se2, Eh, cnt, cnt2);
    k_score  <<<dim3(NROWS / BM, NCB), 256, 0, stream>>>(Zh, Zl, Eh, part);
    k_final  <<<NROWS / 32, 256, 0, stream>>>(part, idx_ws, out_idx, flags, cnt,
                                              cand, ccnt, v2q);
    k_rescan_cand  <<<1024, 256, 0, stream>>>(flags, cnt, cand, ccnt, v2q, z, emb,
                                              se2, idx_ws, out_idx, flags2, cnt2);
    k_fullscan_part<<<2048, 256, 0, stream>>>(flags2, cnt2, z, emb, se2, partial);
    k_fullscan_merge<<<64, 256, 0, stream>>>(flags2, cnt2, partial, idx_ws, out_idx);
    k_zq     <<<dim3(NROWS / 256, 8), 256, 0, stream>>>(idx_ws, emb, inv_e, zq);
}

// Round 9
// 204.698 us; speedup vs baseline: 13.1663x; 1.2577x over previous
//
#include <hip/hip_runtime.h>

#define NUM_E   16384
#define DIM     256
#define NROWS   8192      // B*H*W
#define HW      1024      // H*W
#define BM      128
#define BN      256
#define BK      32
#define NCB     (NUM_E / BN)   // 64 col blocks
#define GATE    2e-3f     // flag threshold (~7 sigma of 2.8e-4 pairwise err)
#define TAUC    2e-3f     // candidate-qualify threshold
#define EHID    2e-3      // hidden-code margin
#define MAXC    16

// 16-B chunk swizzle for staging (chunks 0..3 within a 32-short row)
#define SWZ(r) ((((r) >> 1) ^ ((r) >> 3)) & 3)

typedef __bf16 bf16x8 __attribute__((ext_vector_type(8)));
typedef float  f32x4  __attribute__((ext_vector_type(4)));
typedef float  f32x16 __attribute__((ext_vector_type(16)));

__device__ __forceinline__ unsigned short f2bf(float x) {
    unsigned u = __float_as_uint(x);
    unsigned r = (u + 0x7fffu + ((u >> 16) & 1u)) >> 16;
    return (unsigned short)r;
}
__device__ __forceinline__ void async_copy16(const void* g, void* l) {
    __builtin_amdgcn_global_load_lds(
        (const __attribute__((address_space(1))) unsigned int*)g,
        (__attribute__((address_space(3))) unsigned int*)l, 16, 0, 0);
}

// ---------------- z row sum-of-squares partials (grid 32 x 16) ----------------
__global__ void k_sumz(const float* __restrict__ z, float* __restrict__ zpart) {
    int n = blockIdx.x * 256 + threadIdx.x;
    int b = n >> 10, hw = n & 1023;
    int cb = blockIdx.y;
    const float* p = z + (size_t)(b * DIM + cb * 16) * HW + hw;
    float s = 0.f;
    #pragma unroll
    for (int c = 0; c < 16; c++) { float v = p[c * HW]; s += v * v; }
    zpart[cb * NROWS + n] = s;
}

// ---------------- prep z: finalize inv_z in-block + bf16 split (hi only) ---------
__global__ void k_prep_z(const float* __restrict__ z, const float* __restrict__ zpart,
                         unsigned short* __restrict__ Zh) {
    __shared__ float T[64 * 68];
    __shared__ __align__(16) float Tinv[64];
    int t = threadIdx.x;
    int n0 = blockIdx.x * 64, c0 = blockIdx.y * 64;
    int b = n0 >> 10, hw0 = n0 & 1023;
    if (t < 64) {
        float s = 0.f;
        #pragma unroll
        for (int cb = 0; cb < 16; cb++) s += zpart[cb * NROWS + n0 + t];
        Tinv[t] = 1.0f / fmaxf(sqrtf(s), 1e-12f);
    }
    __syncthreads();
    #pragma unroll
    for (int i = 0; i < 4; i++) {
        int f = t + 256 * i;
        int cc = f >> 4, n4 = (f & 15) * 4;
        float4 v  = *(const float4*)(z + (size_t)(b * DIM + c0 + cc) * HW + hw0 + n4);
        float4 iv = *(const float4*)&Tinv[n4];
        v.x *= iv.x; v.y *= iv.y; v.z *= iv.z; v.w *= iv.w;
        *(float4*)&T[cc * 68 + n4] = v;
    }
    __syncthreads();
    #pragma unroll
    for (int i = 0; i < 4; i++) {
        int f = t + 256 * i;
        int nn = f >> 4, c4 = (f & 15) * 4;
        ushort4 h;
        h.x = f2bf(T[(c4+0)*68 + nn]);
        h.y = f2bf(T[(c4+1)*68 + nn]);
        h.z = f2bf(T[(c4+2)*68 + nn]);
        h.w = f2bf(T[(c4+3)*68 + nn]);
        *(ushort4*)(Zh + (size_t)(n0 + nn) * DIM + c0 + c4) = h;
    }
}

// ---------------- prep e: fp64 norm + bf16 hi ----------------
__global__ void k_prep_e(const float* __restrict__ emb, float* __restrict__ inv_e,
                         double* __restrict__ se2, unsigned short* __restrict__ Eh,
                         int* __restrict__ cnt, int* __restrict__ cnt2) {
    if (blockIdx.x == 0 && threadIdx.x == 0) { *cnt = 0; *cnt2 = 0; }
    int wv = threadIdx.x >> 6, lane = threadIdx.x & 63;
    int k = blockIdx.x * 4 + wv;
    float4 v = *(const float4*)(emb + (size_t)k * DIM + lane * 4);
    double sq = (double)v.x*v.x + (double)v.y*v.y + (double)v.z*v.z + (double)v.w*v.w;
    for (int off = 32; off > 0; off >>= 1) sq += __shfl_down(sq, off);
    double tot = fmax(__shfl(sq, 0), 1e-24);
    if (lane == 0) { se2[k] = tot; inv_e[k] = 1.0f / fmaxf((float)sqrt(tot), 1e-12f); }
    float s = 1.0f / fmaxf((float)sqrt(tot), 1e-12f);
    ushort4 h;
    h.x = f2bf(v.x * s); h.y = f2bf(v.y * s); h.z = f2bf(v.z * s); h.w = f2bf(v.w * s);
    *(ushort4*)(Eh + (size_t)k * DIM + lane * 4) = h;
}

// ---------------- MFMA bf16 1-pass score: zh·eh, folded top-2 epilogue ----------
__launch_bounds__(256, 2)
__global__ void k_score(const unsigned short* __restrict__ Zh,
                        const unsigned short* __restrict__ Eh, f32x4* __restrict__ part) {
    // union: staging A 4096 | B 8192 shorts (24 KB)  /  epilogue vals+idxs 2x8448 f32
    __shared__ __align__(16) float smem[16896];
    unsigned short* lds = (unsigned short*)smem;
    float* vals = smem;
    int*   idxs = (int*)(smem + 8448);
    const int t = threadIdx.x, l = t & 63, w = t >> 6;
    const int wm = w >> 1, wn = w & 1;      // wave tile 64 x 128
    const int m0 = blockIdx.x * BM;
    const int nb = blockIdx.y * BN;
    const int l31 = l & 31, lh = l >> 5;
    const int sr = l >> 2, sp = l & 3;

    const unsigned short* gA0 = Zh + (size_t)m0 * DIM;
    const unsigned short* gB0 = Eh + (size_t)nb * DIM;

    f32x16 acc[2][4];
    #pragma unroll
    for (int i = 0; i < 2; i++)
        #pragma unroll
        for (int j = 0; j < 4; j++) acc[i][j] = (f32x16)0.f;

    for (int kc = 0; kc < DIM; kc += BK) {
        {   // A: 8 subtiles over 4 waves x 2
            #pragma unroll
            for (int h = 0; h < 2; h++) {
                int sub = 4 * h + w;
                int r = sub * 16 + sr;
                int c = sp ^ SWZ(r);
                async_copy16(gA0 + (size_t)r * DIM + kc + c * 8, &lds[sub * 512]);
            }
        }
        #pragma unroll
        for (int h = 0; h < 4; h++) {       // B: 16 subtiles
            int sub = 4 * h + w;
            int r = sub * 16 + sr;
            int c = sp ^ SWZ(r);
            async_copy16(gB0 + (size_t)r * DIM + kc + c * 8, &lds[4096 + sub * 512]);
        }
        __syncthreads();
        #pragma unroll
        for (int s = 0; s < 2; s++) {
            int c = 2 * s + lh;
            bf16x8 ah[2], bh[4];
            #pragma unroll
            for (int i = 0; i < 2; i++) {
                int r = wm * 64 + i * 32 + l31;
                ah[i] = *(const bf16x8*)&lds[r * 32 + ((c ^ SWZ(r)) * 8)];
            }
            #pragma unroll
            for (int j = 0; j < 4; j++) {
                int r = wn * 128 + j * 32 + l31;
                bh[j] = *(const bf16x8*)&lds[4096 + r * 32 + ((c ^ SWZ(r)) * 8)];
            }
            #pragma unroll
            for (int i = 0; i < 2; i++)
                #pragma unroll
                for (int j = 0; j < 4; j++)
                    acc[i][j] = __builtin_amdgcn_mfma_f32_32x32x16_bf16(ah[i], bh[j], acc[i][j], 0, 0, 0);
        }
        __syncthreads();
    }

    // ---- epilogue v2: fold j in-register, pair-dump, scan [64][132] geometry ----
    float VA1 = -2e9f, VA2 = -2e9f, VB1 = -2e9f, VB2 = -2e9f;
    int JA1 = 0, JA2 = 0, JB1 = 0, JB2 = 0;
    const int rl = t >> 2, q = t & 3;
    #pragma unroll
    for (int i = 0; i < 2; i++) {
        #pragma unroll
        for (int reg = 0; reg < 16; reg++) {
            float V1 = -2e9f, V2 = -2e9f; int I1 = 0, I2 = 0;
            #pragma unroll
            for (int j = 0; j < 4; j++) {
                float v = acc[i][j][reg];
                int c = nb + wn * 128 + j * 32 + l31;
                bool g1 = v > V1, g2 = v > V2;
                I2 = g1 ? I1 : (g2 ? c : I2);
                V2 = g1 ? V1 : (g2 ? v : V2);
                I1 = g1 ? c : I1;
                V1 = g1 ? v : V1;
            }
            int rr = wm * 32 + (reg & 3) + 8 * (reg >> 2) + 4 * lh;
            int s0 = wn * 64 + l31 * 2;           // even; s0,s0+1 share a 32-chunk
            int a0 = rr * 132 + (s0 >> 5) * 33 + (s0 & 31);
            vals[a0] = V1; vals[a0 + 1] = V2;
            idxs[a0] = I1; idxs[a0 + 1] = I2;
        }
        __syncthreads();
        // scan: thread (rl 0..63, q 0..3) covers slots q*32..+31 of local row rl
        float V1 = -2e9f, V2 = -2e9f; int I1 = 0, I2 = 0;
        const float* pv = &vals[rl * 132 + q * 33];
        const int*   pi = &idxs[rl * 132 + q * 33];
        #pragma unroll
        for (int u = 0; u < 32; u++) {
            float v = pv[u]; int c = pi[u];
            bool g1 = v > V1, g2 = v > V2;
            I2 = g1 ? I1 : (g2 ? c : I2);
            V2 = g1 ? V1 : (g2 ? v : V2);
            I1 = g1 ? c : I1;
            V1 = g1 ? v : V1;
        }
        __syncthreads();
        #pragma unroll
        for (int d = 1; d <= 2; d <<= 1) {
            float oV1 = __shfl_down(V1, d), oV2 = __shfl_down(V2, d);
            int   oI1 = __shfl_down(I1, d), oI2 = __shfl_down(I2, d);
            bool o1 = oV1 > V1;
            float mn = o1 ? V1 : oV1; int mni = o1 ? I1 : oI1;
            V1 = o1 ? oV1 : V1; I1 = o1 ? oI1 : I1;
            bool s2 = oV2 > V2;
            float m2 = s2 ? oV2 : V2; int m2i = s2 ? oI2 : I2;
            bool c2 = m2 > mn;
            V2 = c2 ? m2 : mn; I2 = c2 ? m2i : mni;
        }
        if (i == 0) {
            bool o1 = V1 > VA1;
            float mn = o1 ? VA1 : V1; int mni = o1 ? JA1 : I1;
            VA1 = o1 ? V1 : VA1; JA1 = o1 ? I1 : JA1;
            bool s2 = V2 > VA2;
            float m2 = s2 ? V2 : VA2; int m2i = s2 ? I2 : JA2;
            bool c2 = m2 > mn;
            VA2 = c2 ? m2 : mn; JA2 = c2 ? m2i : mni;
        } else {
            bool o1 = V1 > VB1;
            float mn = o1 ? VB1 : V1; int mni = o1 ? JB1 : I1;
            VB1 = o1 ? V1 : VB1; JB1 = o1 ? I1 : JB1;
            bool s2 = V2 > VB2;
            float m2 = s2 ? V2 : VB2; int m2i = s2 ? I2 : JB2;
            bool c2 = m2 > mn;
            VB2 = c2 ? m2 : mn; JB2 = c2 ? m2i : mni;
        }
    }
    if ((t & 3) == 0) {
        int rowA = (rl >> 5) * 64 + (rl & 31);   // i=0 rows
        int rowB = rowA + 32;                     // i=1 rows
        f32x4 ea; ea[0] = VA1; ea[1] = __int_as_float(JA1);
        ea[2] = VA2; ea[3] = __int_as_float(JA2);
        part[(size_t)blockIdx.y * NROWS + m0 + rowA] = ea;
        f32x4 eb; eb[0] = VB1; eb[1] = __int_as_float(JB1);
        eb[2] = VB2; eb[3] = __int_as_float(JB2);
        part[(size_t)blockIdx.y * NROWS + m0 + rowB] = eb;
    }
}

// ---------------- reduce + flag near-ties + collect block-top-2 candidates -------
__global__ void k_final(const f32x4* __restrict__ part, int* __restrict__ idx_ws,
                        float* __restrict__ out_idx, int* __restrict__ flags,
                        int* __restrict__ cnt, int* __restrict__ cand,
                        int* __restrict__ ccnt, float* __restrict__ v2q) {
    __shared__ f32x4 red[8][32];
    __shared__ float bcV1[32], bcV2[32];
    __shared__ int   lcc[32];
    __shared__ int   lcand[32][MAXC];
    __shared__ float sv2[8][32];
    const int nl = threadIdx.x & 31, sc = threadIdx.x >> 5;
    const int n = blockIdx.x * 32 + nl;
    if (threadIdx.x < 32) lcc[threadIdx.x] = 0;
    float V1 = -2e9f, V2 = -2e9f; int I1 = 0;
    for (int s = sc * 8; s < sc * 8 + 8; s++) {
        f32x4 e = part[(size_t)s * NROWS + n];
        float v1 = e[0]; int i1 = __float_as_int(e[1]); float v2 = e[2];
        V2 = fmaxf(fmaxf(V2, v2), fminf(v1, V1));
        I1 = (v1 > V1) ? i1 : I1;
        V1 = fmaxf(V1, v1);
    }
    f32x4 me; me[0] = V1; me[1] = __int_as_float(I1); me[2] = V2; me[3] = 0.f;
    red[sc][nl] = me;
    __syncthreads();
    if (threadIdx.x < 32) {
        float W1 = -2e9f, W2 = -2e9f; int J1 = 0;
        #pragma unroll
        for (int s2 = 0; s2 < 8; s2++) {
            f32x4 e = red[s2][threadIdx.x];
            float v1 = e[0]; int i1 = __float_as_int(e[1]); float v2 = e[2];
            W2 = fmaxf(fmaxf(W2, v2), fminf(v1, W1));
            J1 = (v1 > W1) ? i1 : J1;
            W1 = fmaxf(W1, v1);
        }
        int nn = blockIdx.x * 32 + threadIdx.x;
        idx_ws[nn] = J1;
        out_idx[nn] = (float)J1;
        bcV1[threadIdx.x] = W1;
        bcV2[threadIdx.x] = W2;
    }
    __syncthreads();
    float thr = bcV1[nl] - TAUC;
    float lv2 = -2e9f;
    for (int s = sc * 8; s < sc * 8 + 8; s++) {
        f32x4 e = part[(size_t)s * NROWS + n];
        if (e[0] >= thr) {
            int pos = atomicAdd(&lcc[nl], 2);
            if (pos < MAXC)     lcand[nl][pos]     = __float_as_int(e[1]);
            if (pos + 1 < MAXC) lcand[nl][pos + 1] = __float_as_int(e[3]);
            lv2 = fmaxf(lv2, e[2]);
        }
    }
    sv2[sc][nl] = lv2;
    __syncthreads();
    if (threadIdx.x < 32) {
        int nn = blockIdx.x * 32 + threadIdx.x;
        float W1 = bcV1[threadIdx.x], W2 = bcV2[threadIdx.x];
        if (W1 - W2 < GATE) {
            float m = -2e9f;
            #pragma unroll
            for (int s2 = 0; s2 < 8; s2++) m = fmaxf(m, sv2[s2][threadIdx.x]);
            int p = atomicAdd(cnt, 1);
            flags[p] = nn;
            ccnt[nn] = lcc[threadIdx.x];
            v2q[nn] = m;
            #pragma unroll
            for (int j = 0; j < MAXC; j++) cand[nn * MAXC + j] = lcand[threadIdx.x][j];
        }
    }
}

// ---------------- fp64 rescore of candidate columns (block per flagged row) ------
__launch_bounds__(256)
__global__ void k_rescan_cand(const int* __restrict__ flags, const int* __restrict__ cnt,
                              const int* __restrict__ cand, const int* __restrict__ ccnt,
                              const float* __restrict__ v2q,
                              const float* __restrict__ z, const float* __restrict__ emb,
                              const double* __restrict__ se2,
                              int* __restrict__ idx_ws, float* __restrict__ out_idx,
                              int* __restrict__ flags2, int* __restrict__ cnt2) {
    __shared__ double zs[DIM];
    __shared__ double wv[4];
    __shared__ int    wi[4];
    const int t = threadIdx.x, l = t & 63, w = t >> 6;
    const int F = *cnt;
    for (int f = blockIdx.x; f < F; f += gridDim.x) {
        int n = flags[f];
        int C = ccnt[n];
        int b = n >> 10, hw = n & 1023;
        __syncthreads();
        zs[t] = (double)z[(size_t)(b * DIM + t) * HW + hw];
        __syncthreads();
        double best = -2e18; int bi = 0x7fffffff;
        if (C <= MAXC) {
            double z0 = zs[l*4], z1 = zs[l*4+1], z2 = zs[l*4+2], z3 = zs[l*4+3];
            for (int cix = w; cix < C; cix += 4) {
                int k = cand[n * MAXC + cix];
                float4 ev = *(const float4*)(emb + (size_t)k * DIM + l * 4);
                double d = z0 * (double)ev.x + z1 * (double)ev.y
                         + z2 * (double)ev.z + z3 * (double)ev.w;
                #pragma unroll
                for (int o = 32; o > 0; o >>= 1) d += __shfl_down(d, o);
                if (l == 0) {
                    double qv = d / sqrt(se2[k]);
                    if (qv > best || (qv == best && k < bi)) { best = qv; bi = k; }
                }
            }
        }
        if (l == 0) { wv[w] = best; wi[w] = bi; }
        __syncthreads();
        if (t == 0) {
            if (C > MAXC) {
                int p = atomicAdd(cnt2, 1); flags2[p] = n;
            } else {
                double B = wv[0]; int BI = wi[0];
                #pragma unroll
                for (int x = 1; x < 4; x++)
                    if (wv[x] > B || (wv[x] == B && wi[x] < BI)) { B = wv[x]; BI = wi[x]; }
                if ((double)v2q[n] >= B - EHID) {
                    int p = atomicAdd(cnt2, 1); flags2[p] = n;   // possible hidden code
                } else {
                    idx_ws[n] = BI; out_idx[n] = (float)BI;
                }
            }
        }
    }
}

// ---------------- rare fallback: full fp64 scan (parallel over row x split) ------
__launch_bounds__(256)
__global__ void k_fullscan_part(const int* __restrict__ flags2, const int* __restrict__ cnt2,
                                const float* __restrict__ z, const float* __restrict__ emb,
                                const double* __restrict__ se2, double2* __restrict__ partial) {
    __shared__ double zs[DIM];
    __shared__ double wv[4];
    __shared__ int    wi[4];
    const int t = threadIdx.x, l = t & 63, w = t >> 6;
    const int W = (*cnt2) * 64;
    for (int item = blockIdx.x; item < W; item += gridDim.x) {
        int f = item >> 6, split = item & 63;
        int n = flags2[f];
        int b = n >> 10, hw = n & 1023;
        __syncthreads();
        zs[t] = (double)z[(size_t)(b * DIM + t) * HW + hw];
        __syncthreads();
        double z0 = zs[l*4], z1 = zs[l*4+1], z2 = zs[l*4+2], z3 = zs[l*4+3];
        double best = -2e18; int bi = 0;
        int kbase = split * 256 + w * 64;
        for (int p = 0; p < 64; p++) {
            int k = kbase + p;
            float4 ev = *(const float4*)(emb + (size_t)k * DIM + l * 4);
            double d = z0 * (double)ev.x + z1 * (double)ev.y
                     + z2 * (double)ev.z + z3 * (double)ev.w;
            #pragma unroll
            for (int o = 32; o > 0; o >>= 1) d += __shfl_down(d, o);
            if (l == 0) {
                double qv = d / sqrt(se2[k]);
                if (qv > best) { best = qv; bi = k; }
            }
        }
        if (l == 0) { wv[w] = best; wi[w] = bi; }
        __syncthreads();
        if (t == 0) {
            double B = wv[0]; int BI = wi[0];
            #pragma unroll
            for (int x = 1; x < 4; x++)
                if (wv[x] > B || (wv[x] == B && wi[x] < BI)) { B = wv[x]; BI = wi[x]; }
            partial[item] = make_double2(B, (double)BI);
        }
        __syncthreads();
    }
}

__global__ void k_fullscan_merge(const int* __restrict__ flags2, const int* __restrict__ cnt2,
                                 const double2* __restrict__ partial,
                                 int* __restrict__ idx_ws, float* __restrict__ out_idx) {
    const int F = *cnt2;
    const int l = threadIdx.x & 63, w = threadIdx.x >> 6;
    for (int f = blockIdx.x * 4 + w; f < F; f += gridDim.x * 4) {
        double2 e = partial[(size_t)f * 64 + l];
        double v = e.x; int i = (int)e.y;
        #pragma unroll
        for (int o = 32; o > 0; o >>= 1) {
            double ov = __shfl_down(v, o);
            int    oi = __shfl_down(i, o);
            if (ov > v || (ov == v && oi < i)) { v = ov; i = oi; }
        }
        if (l == 0) { int n = flags2[f]; idx_ws[n] = i; out_idx[n] = (float)i; }
    }
}

// ---------------- gather z_q = emb[idx] * inv_e[idx], grid (32, 8) ----------------
__global__ void k_zq(const int* __restrict__ idx_ws, const float* __restrict__ emb,
                     const float* __restrict__ inv_e, float* __restrict__ zq) {
    int t = threadIdx.x;
    int n = blockIdx.x * 256 + t;
    int b = n >> 10, hw = n & 1023;
    int c0 = blockIdx.y * 32;
    int id = idx_ws[n];
    float s = inv_e[id];
    const float* er = emb + (size_t)id * DIM;
    #pragma unroll
    for (int cc = 0; cc < 32; cc += 4) {
        float4 a = *(const float4*)(er + c0 + cc);
        zq[(size_t)(b * DIM + c0 + cc + 0) * HW + hw] = a.x * s;
        zq[(size_t)(b * DIM + c0 + cc + 1) * HW + hw] = a.y * s;
        zq[(size_t)(b * DIM + c0 + cc + 2) * HW + hw] = a.z * s;
        zq[(size_t)(b * DIM + c0 + cc + 3) * HW + hw] = a.w * s;
    }
}

extern "C" void kernel_launch(void* const* d_in, const int* in_sizes, int n_in,
                              void* d_out, int out_size, void* d_ws, size_t ws_size,
                              hipStream_t stream) {
    const float* z   = (const float*)d_in[0];
    const float* emb = (const float*)d_in[1];

    unsigned short* Zh = (unsigned short*)d_ws;           // 4 MB
    unsigned short* Eh = Zh + (size_t)NROWS * DIM;        // 8 MB
    float*  inv_e = (float*)(Eh + (size_t)NUM_E * DIM);   // 64 KB
    float*  zpart = inv_e + NUM_E;                        // 512 KB
    int*    idx_ws = (int*)(zpart + 16 * NROWS);          // 32 KB
    double* se2   = (double*)(idx_ws + NROWS);            // 128 KB
    int*    flags = (int*)(se2 + NUM_E);                  // 32 KB
    int*    flags2 = flags + NROWS;                       // 32 KB
    int*    cand  = flags2 + NROWS;                       // 512 KB (16/row)
    int*    ccnt  = cand + NROWS * MAXC;                  // 32 KB
    float*  v2q   = (float*)(ccnt + NROWS);               // 32 KB
    int*    cnt   = (int*)(v2q + NROWS);                  // 4 B
    int*    cnt2  = cnt + 1;                              // 4 B

    float* zq      = (float*)d_out;
    float* out_idx = zq + (size_t)NROWS * DIM;
    // part (8 MB) aliases the z_q region; consumed by k_final, then reused for
    // fullscan partials, finally overwritten with z_q by k_zq.
    f32x4*   part    = (f32x4*)zq;
    double2* partial = (double2*)zq;

    k_sumz   <<<dim3(NROWS / 256, 16), 256, 0, stream>>>(z, zpart);
    k_prep_z <<<dim3(NROWS / 64, DIM / 64), 256, 0, stream>>>(z, zpart, Zh);
    k_prep_e <<<NUM_E / 4, 256, 0, stream>>>(emb, inv_e, se2, Eh, cnt, cnt2);
    k_score  <<<dim3(NROWS / BM, NCB), 256, 0, stream>>>(Zh, Eh, part);
    k_final  <<<NROWS / 32, 256, 0, stream>>>(part, idx_ws, out_idx, flags, cnt,
                                              cand, ccnt, v2q);
    k_rescan_cand  <<<1024, 256, 0, stream>>>(flags, cnt, cand, ccnt, v2q, z, emb,
                                              se2, idx_ws, out_idx, flags2, cnt2);
    k_fullscan_part<<<2048, 256, 0, stream>>>(flags2, cnt2, z, emb, se2, partial);
    k_fullscan_merge<<<64, 256, 0, stream>>>(flags2, cnt2, partial, idx_ws, out_idx);
    k_zq     <<<dim3(NROWS / 256, 8), 256, 0, stream>>>(idx_ws, emb, inv_e, zq);
}